// Round 5
// baseline (1793.077 us; speedup 1.0000x reference)
//
#include <hip/hip_runtime.h>
#include <stdint.h>

// ---------------------------------------------------------------------------
// MultiGraph hetero-GNN + gumbel-top-k edge pruning, fp32 throughout.
// Round 5: dispatch-count collapse. Two grid-resident mega-kernels with
// software grid barriers replace 11 small dispatches (theory: ~13us/dispatch
// launch gap dominates). Per-work-item code r4-identical (bit-exact).
// PRNG: JAX threefry2x32, partitionable path (verified absmax=0.0 r1-r4).
// ---------------------------------------------------------------------------

namespace {

constexpr int NPn = 4096;
constexpr int NAn = 2048;
constexpr int Hh  = 128;
constexpr int EPPc = 131072;
constexpr int EAAc = 65536;
constexpr int KSEL = 5;
constexpr int GRID = 768;     // mega grids: 3 blocks/CU co-resident (launch_bounds(256,3))

// CSR segments: 0 pp-dst, 1 aa-dst, 2 pa-dst, 3 ap-dst, 4 pp-src, 5 aa-src
// rowptr offsets: 0, 4097, 6146, 8195, 12292, 16389 (each N+1)
// entry offsets:  0, 131072, 196608, 327680, 458752, 589824 (total 655360)

__host__ __device__ static inline void tf2x32(uint32_t k0, uint32_t k1,
                                              uint32_t& x0, uint32_t& x1) {
  uint32_t ks2 = k0 ^ k1 ^ 0x1BD11BDAu;
  x0 += k0; x1 += k1;
#define TF_R(r) { x0 += x1; x1 = (x1 << (r)) | (x1 >> (32 - (r))); x1 ^= x0; }
  TF_R(13) TF_R(15) TF_R(26) TF_R(6)
  x0 += k1;  x1 += ks2 + 1u;
  TF_R(17) TF_R(29) TF_R(16) TF_R(24)
  x0 += ks2; x1 += k0 + 2u;
  TF_R(13) TF_R(15) TF_R(26) TF_R(6)
  x0 += k0;  x1 += k1 + 3u;
  TF_R(17) TF_R(29) TF_R(16) TF_R(24)
  x0 += k1;  x1 += ks2 + 4u;
  TF_R(13) TF_R(15) TF_R(26) TF_R(6)
  x0 += ks2; x1 += k0 + 5u;
#undef TF_R
}

// ---------------- shared-memory union for mega kernels ----------------
union __align__(16) SharedU {
  int scratch4[4];                                   // scan wave sums
  struct { float A[2 * 32 * 68]; float W[2 * 32 * 68]; } gm;  // dbuf GEMM (34.8 KB)
  struct { float selfr[128], mpp[128], mapr[128], t[128]; } fin;
};

// ---------------- software grid barrier (device-scope; cooperative pattern) -------------
__device__ __forceinline__ void gbar(int* ctr, int nblk)
{
  __syncthreads();
  if (threadIdx.x == 0) {
    __threadfence();   // release: flush my L2 (cross-XCD visibility)
    __hip_atomic_fetch_add(ctr, 1, __ATOMIC_RELEASE, __HIP_MEMORY_SCOPE_AGENT);
    while (__hip_atomic_load(ctr, __ATOMIC_RELAXED, __HIP_MEMORY_SCOPE_AGENT) < nblk) {
      __builtin_amdgcn_s_sleep(2);
    }
    __threadfence();   // acquire: invalidate stale L1/L2 lines
  }
  __syncthreads();
}

// ---------------- batched mean aggregation (r4 body, grid-stride) -----------------------
struct AggSeg { const float* h; const float* w; float* M; int rpOff; int enOff; int shift; };
struct AggSet { AggSeg s[4]; int start[5]; int nseg; };

__device__ __forceinline__ void agg_run(const AggSet& a, const int* __restrict__ rowptr,
                                        const int* __restrict__ entries)
{
  int total = a.start[a.nseg];
  int fl = (threadIdx.x & 31) << 2;              // float4 feature offset
  for (int g = blockIdx.x * 8 + (threadIdx.x >> 5); g < total; g += gridDim.x * 8) {
    int si = 0;
    while (si < a.nseg - 1 && g >= a.start[si + 1]) ++si;
    AggSeg sg = a.s[si];
    int node = g - a.start[si];
    const int* rp = rowptr + sg.rpOff;
    const int* ent = entries + sg.enOff;
    int b = rp[node], e = rp[node + 1];
    const float* h = sg.h;
    int sh = sg.shift;
    float ax = 0.f, ay = 0.f, az = 0.f, aw = 0.f;
    if (sg.w) {
      unsigned mask = (1u << sh) - 1u;
      int k = b;
      for (; k + 3 < e; k += 4) {
        unsigned p0 = (unsigned)ent[k], p1 = (unsigned)ent[k + 1];
        unsigned p2 = (unsigned)ent[k + 2], p3 = (unsigned)ent[k + 3];
        float w0 = sg.w[p0 & mask], w1 = sg.w[p1 & mask];
        float w2v = sg.w[p2 & mask], w3 = sg.w[p3 & mask];
        float4 v0, v1, v2, v3;
        if (w0 != 0.f) v0 = *(const float4*)&h[(size_t)(p0 >> sh) * Hh + fl];
        if (w1 != 0.f) v1 = *(const float4*)&h[(size_t)(p1 >> sh) * Hh + fl];
        if (w2v != 0.f) v2 = *(const float4*)&h[(size_t)(p2 >> sh) * Hh + fl];
        if (w3 != 0.f) v3 = *(const float4*)&h[(size_t)(p3 >> sh) * Hh + fl];
        if (w0 != 0.f) { ax += v0.x; ay += v0.y; az += v0.z; aw += v0.w; }
        if (w1 != 0.f) { ax += v1.x; ay += v1.y; az += v1.z; aw += v1.w; }
        if (w2v != 0.f) { ax += v2.x; ay += v2.y; az += v2.z; aw += v2.w; }
        if (w3 != 0.f) { ax += v3.x; ay += v3.y; az += v3.z; aw += v3.w; }
      }
      for (; k < e; ++k) {
        unsigned pl = (unsigned)ent[k];
        float wt = sg.w[pl & mask];
        if (wt != 0.f) {
          float4 v = *(const float4*)&h[(size_t)(pl >> sh) * Hh + fl];
          ax += v.x; ay += v.y; az += v.z; aw += v.w;
        }
      }
    } else {
      int k = b;
      for (; k + 3 < e; k += 4) {
        unsigned p0 = (unsigned)ent[k], p1 = (unsigned)ent[k + 1];
        unsigned p2 = (unsigned)ent[k + 2], p3 = (unsigned)ent[k + 3];
        float4 v0 = *(const float4*)&h[(size_t)(p0 >> sh) * Hh + fl];
        float4 v1 = *(const float4*)&h[(size_t)(p1 >> sh) * Hh + fl];
        float4 v2 = *(const float4*)&h[(size_t)(p2 >> sh) * Hh + fl];
        float4 v3 = *(const float4*)&h[(size_t)(p3 >> sh) * Hh + fl];
        ax += v0.x; ay += v0.y; az += v0.z; aw += v0.w;
        ax += v1.x; ay += v1.y; az += v1.z; aw += v1.w;
        ax += v2.x; ay += v2.y; az += v2.z; aw += v2.w;
        ax += v3.x; ay += v3.y; az += v3.z; aw += v3.w;
      }
      for (; k < e; ++k) {
        unsigned pl = (unsigned)ent[k];
        float4 v = *(const float4*)&h[(size_t)(pl >> sh) * Hh + fl];
        ax += v.x; ay += v.y; az += v.z; aw += v.w;
      }
    }
    float cd = fmaxf((float)(e - b), 1.0f);
    float4 o; o.x = ax / cd; o.y = ay / cd; o.z = az / cd; o.w = aw / cd;
    *(float4*)&sg.M[(size_t)node * Hh + fl] = o;
  }
}

// ---------------- batched multi-part fp32 GEMM (r4 dbuf body, grid-stride tiles) --------
struct GDesc {
  const float* A0; const float* W0; const float* A1; const float* W1;
  const float* A2; const float* W2; float* C; int M; int N; int parts; int relu;
};
struct GSet { GDesc d[4]; int bstart[5]; int nd; };

__device__ __forceinline__ void gemm_run(const GSet& g, float* AsB, float* WsB)
{
  int tid = threadIdx.x;
  int tr = tid >> 4, tc = tid & 15;
  int r = tid >> 3, f = tid & 7;
  int nblk = g.bstart[g.nd];
  for (int blk = blockIdx.x; blk < nblk; blk += gridDim.x) {
    int di = 0;
    while (di < g.nd - 1 && blk >= g.bstart[di + 1]) ++di;
    GDesc D = g.d[di];
    int local = blk - g.bstart[di];
    int nT = D.N >> 6;
    int m0 = (local / nT) << 6, n0 = (local % nT) << 6;
    int N = D.N;
    const float* Ap[3] = {D.A0, D.A1, D.A2};
    const float* Wp[3] = {D.W0, D.W1, D.W2};
    int T = D.parts << 2;
    float acc[4][4] = {{0.f}};
    float4 va0, va1, vw0, vw1;
#define LDCH(t_) { const float* A = Ap[(t_) >> 2]; const float* W = Wp[(t_) >> 2]; \
    int k0 = ((t_) & 3) << 5; \
    va0 = *(const float4*)&A[(size_t)(m0 + r) * 128 + k0 + f * 4]; \
    va1 = *(const float4*)&A[(size_t)(m0 + r + 32) * 128 + k0 + f * 4]; \
    vw0 = *(const float4*)&W[(size_t)(k0 + r) * N + n0 + f * 4]; \
    vw1 = *(const float4*)&W[(size_t)(k0 + r) * N + n0 + f * 4 + 32]; }
#define STCH(b_) { \
    AsB[((b_) * 32 + f * 4 + 0) * 68 + r] = va0.x; \
    AsB[((b_) * 32 + f * 4 + 1) * 68 + r] = va0.y; \
    AsB[((b_) * 32 + f * 4 + 2) * 68 + r] = va0.z; \
    AsB[((b_) * 32 + f * 4 + 3) * 68 + r] = va0.w; \
    AsB[((b_) * 32 + f * 4 + 0) * 68 + r + 32] = va1.x; \
    AsB[((b_) * 32 + f * 4 + 1) * 68 + r + 32] = va1.y; \
    AsB[((b_) * 32 + f * 4 + 2) * 68 + r + 32] = va1.z; \
    AsB[((b_) * 32 + f * 4 + 3) * 68 + r + 32] = va1.w; \
    *(float4*)&WsB[((b_) * 32 + r) * 68 + f * 4] = vw0; \
    *(float4*)&WsB[((b_) * 32 + r) * 68 + f * 4 + 32] = vw1; }
    LDCH(0); STCH(0);
    __syncthreads();
    for (int t = 0; t < T; ++t) {
      int cur = t & 1;
      bool more = (t + 1 < T);
      if (more) LDCH(t + 1);
#pragma unroll
      for (int k = 0; k < 32; ++k) {
        float4 a = *(const float4*)&AsB[(cur * 32 + k) * 68 + tr * 4];
        float4 b = *(const float4*)&WsB[(cur * 32 + k) * 68 + tc * 4];
        acc[0][0] += a.x * b.x; acc[0][1] += a.x * b.y; acc[0][2] += a.x * b.z; acc[0][3] += a.x * b.w;
        acc[1][0] += a.y * b.x; acc[1][1] += a.y * b.y; acc[1][2] += a.y * b.z; acc[1][3] += a.y * b.w;
        acc[2][0] += a.z * b.x; acc[2][1] += a.z * b.y; acc[2][2] += a.z * b.z; acc[2][3] += a.z * b.w;
        acc[3][0] += a.w * b.x; acc[3][1] += a.w * b.y; acc[3][2] += a.w * b.z; acc[3][3] += a.w * b.w;
      }
      if (more) STCH(cur ^ 1);
      __syncthreads();
    }
#pragma unroll
    for (int i = 0; i < 4; ++i) {
      float4 v;
      v.x = acc[i][0]; v.y = acc[i][1]; v.z = acc[i][2]; v.w = acc[i][3];
      if (D.relu) {
        v.x = fmaxf(v.x, 0.f); v.y = fmaxf(v.y, 0.f);
        v.z = fmaxf(v.z, 0.f); v.w = fmaxf(v.w, 0.f);
      }
      *(float4*)&D.C[(size_t)(m0 + tr * 4 + i) * N + n0 + tc * 4] = v;
    }
#undef LDCH
#undef STCH
  }
}

// ---------------- mega1: hist | scan | scatter | agg1 | gemm1 | agg2 | gemm2 | Pgemm ----
struct Mega1Args {
  const int *spp, *dpp, *saa, *daa, *spa, *dpa, *sap, *dap;
  int *cnt, *rowptr, *cursor, *entries, *gctr;
  AggSet agg1, agg2;
  GSet gemm1, gemm2, gemmP;
};

__global__ __launch_bounds__(256, 3) void mega1(Mega1Args P)
{
  __shared__ SharedU su;
  int nblk = gridDim.x;
  // ---- phase 0: histogram (order-insensitive atomics) ----
  for (int i = blockIdx.x * 256 + threadIdx.x; i < 655360; i += gridDim.x * 256) {
    const int* kp; int co, e;
    if      (i < 131072) { kp = P.dpp; co = 0;     e = i; }
    else if (i < 196608) { kp = P.daa; co = 4096;  e = i - 131072; }
    else if (i < 327680) { kp = P.dpa; co = 6144;  e = i - 196608; }
    else if (i < 458752) { kp = P.dap; co = 8192;  e = i - 327680; }
    else if (i < 589824) { kp = P.spp; co = 12288; e = i - 458752; }
    else                 { kp = P.saa; co = 16384; e = i - 589824; }
    atomicAdd(&P.cnt[co + kp[e]], 1);
  }
  gbar(P.gctr + 0, nblk);
  // ---- phase 1: exclusive scan (6 relations, blocks 0-5, r4 code) ----
  if (blockIdx.x < 6) {
    const int Ns[6]   = {4096, 2048, 2048, 4096, 4096, 2048};
    const int coff[6] = {0, 4096, 6144, 8192, 12288, 16384};
    const int roff[6] = {0, 4097, 6146, 8195, 12292, 16389};
    int rel = blockIdx.x, tid = threadIdx.x;
    int N = Ns[rel], co = coff[rel], ro = roff[rel];
    int per = N >> 8;
    int base = tid * per;
    int local[16];
    int s = 0;
    for (int i = 0; i < per; ++i) { local[i] = s; s += P.cnt[co + base + i]; }
    int lane = tid & 63, wv = tid >> 6;
    int x = s;
    for (int d = 1; d < 64; d <<= 1) {
      int y = __shfl_up(x, d);
      if (lane >= d) x += y;
    }
    if (lane == 63) su.scratch4[wv] = x;
    __syncthreads();
    int woff = 0;
    for (int q = 0; q < wv; ++q) woff += su.scratch4[q];
    int excl = woff + x - s;
    for (int i = 0; i < per; ++i) {
      int v = excl + local[i];
      P.rowptr[ro + base + i] = v;
      P.cursor[co + base + i] = v;
    }
    if (tid == 255) P.rowptr[ro + N] = excl + s;
  }
  gbar(P.gctr + 1, nblk);
  // ---- phase 2: scatter (same thread->edge mapping structure as r4) ----
  for (int i = blockIdx.x * 256 + threadIdx.x; i < 655360; i += gridDim.x * 256) {
    int key, pl, co, eo;
    if (i < 131072) {
      int e = i;
      key = P.dpp[e]; pl = (P.spp[e] << 18) | e; co = 0; eo = 0;
    } else if (i < 196608) {
      int e = i - 131072;
      key = P.daa[e]; pl = (P.saa[e] << 16) | e; co = 4096; eo = 131072;
    } else if (i < 327680) {
      int e = i - 196608;
      key = P.dpa[e]; pl = P.spa[e]; co = 6144; eo = 196608;
    } else if (i < 458752) {
      int e = i - 327680;
      key = P.dap[e]; pl = P.sap[e]; co = 8192; eo = 327680;
    } else if (i < 589824) {
      int e = i - 458752;
      key = P.spp[e]; pl = (P.dpp[e] << 18) | e; co = 12288; eo = 458752;
    } else {
      int e = i - 589824;
      key = P.saa[e]; pl = (P.daa[e] << 16) | e; co = 16384; eo = 589824;
    }
    int pos = atomicAdd(&P.cursor[co + key], 1);
    P.entries[eo + pos] = pl;
  }
  gbar(P.gctr + 2, nblk);
  // ---- GNN1 layer 0 ----
  agg_run(P.agg1, P.rowptr, P.entries);
  gbar(P.gctr + 3, nblk);
  gemm_run(P.gemm1, su.gm.A, su.gm.W);
  gbar(P.gctr + 4, nblk);
  // ---- GNN1 layer 1 ----
  agg_run(P.agg2, P.rowptr, P.entries);
  gbar(P.gctr + 5, nblk);
  gemm_run(P.gemm2, su.gm.A, su.gm.W);
  gbar(P.gctr + 6, nblk);
  // ---- edge-MLP node projections ----
  gemm_run(P.gemmP, su.gm.A, su.gm.W);
}

// ---------------- mega2: agg3 | gemm3 | final -------------------------------------------
struct Mega2Args {
  const int* rowptr; const int* entries; int* gctr;
  AggSet agg3;
  GSet gemm3;
  const float *hp, *ha, *wpp, *Wself, *Wpp, *Wap, *Wc, *bc;
  const int* idxPtr;
  float* out;
};

__global__ __launch_bounds__(256, 3) void mega2(Mega2Args P)
{
  __shared__ SharedU su;
  int nblk = gridDim.x;
  agg_run(P.agg3, P.rowptr, P.entries);
  gbar(P.gctr + 8, nblk);
  gemm_run(P.gemm3, su.gm.A, su.gm.W);
  gbar(P.gctr + 9, nblk);
  // ---- fused GNN2-layer1 (single row) + classifier, block 0 only (r4 code) ----
  if (blockIdx.x != 0) return;
  int tid = threadIdx.x;
  bool act = tid < 128;
  int idx = P.idxPtr[0];
  const int* rp_ppd = P.rowptr + 0;
  const int* ent_ppd = P.entries + 0;
  const int* rp_apd = P.rowptr + 8195;
  const int* ent_apd = P.entries + 327680;
  if (act) {
    su.fin.selfr[tid] = P.hp[(size_t)idx * 128 + tid];
    {
      int b = rp_ppd[idx], e2 = rp_ppd[idx + 1];
      float acc = 0.f;
      for (int k = b; k < e2; ++k) {
        unsigned pl = (unsigned)ent_ppd[k];
        int s = (int)(pl >> 18);
        int e = (int)(pl & 0x3FFFFu);
        acc += P.wpp[e] * P.hp[(size_t)s * 128 + tid];
      }
      su.fin.mpp[tid] = acc / fmaxf((float)(e2 - b), 1.0f);
    }
    {
      int b = rp_apd[idx], e2 = rp_apd[idx + 1];
      float acc = 0.f;
      for (int k = b; k < e2; ++k) {
        int s = ent_apd[k];
        acc += P.ha[(size_t)s * 128 + tid];
      }
      su.fin.mapr[tid] = acc / fmaxf((float)(e2 - b), 1.0f);
    }
  }
  __syncthreads();
  if (act) {
    float s = 0.f;
    for (int m = 0; m < 128; ++m) {
      s += su.fin.selfr[m] * P.Wself[m * 128 + tid] +
           su.fin.mpp[m]   * P.Wpp[m * 128 + tid] +
           su.fin.mapr[m]  * P.Wap[m * 128 + tid];
    }
    su.fin.t[tid] = fmaxf(s, 0.f);
  }
  __syncthreads();
  if (act && tid < 5) {
    float y = P.bc[tid];
    for (int k = 0; k < 128; ++k) y += su.fin.t[k] * P.Wc[k * 5 + tid];
    P.out[tid] = y;
  }
}

// ---------------- fused edge-MLP + coalesce + masked gumbel top-5 + w write -------------
// Verbatim r4 (standalone dispatch: keeps 7 blocks/CU occupancy for the P2 gathers).
__global__ __launch_bounds__(256) void row_topk(
    const float* __restrict__ P1pp, const float* __restrict__ P2pp,
    const float* __restrict__ b1pp, const float* __restrict__ W2pp,
    const float* __restrict__ b2pp,
    const float* __restrict__ P1aa, const float* __restrict__ P2aa,
    const float* __restrict__ b1aa, const float* __restrict__ W2aa,
    const float* __restrict__ b2aa,
    const int* __restrict__ rowptr, const int* __restrict__ entries,
    float* __restrict__ w_pp, float* __restrict__ w_aa,
    uint32_t kpp0, uint32_t kpp1, uint32_t kaa0, uint32_t kaa1)
{
  __shared__ float ys[4096];
  __shared__ float P1s[256], b1s[256], w2s[256];
  __shared__ float scrF[256];
  __shared__ int   scrI[256];
  __shared__ int   sel5[KSEL];
  __shared__ int   candCnt;
  int blk = blockIdx.x, tid = threadIdx.x;
  int lane = tid & 63, wv = tid >> 6;
  int row, Ncols, shift; unsigned mask;
  const float* P1; const float* P2; const float* b1; const float* W2; const float* b2;
  const int* rp; const int* ent; float* wout; uint32_t k0, k1;
  if (blk < NPn) {
    row = blk; Ncols = NPn; shift = 18; mask = 0x3FFFFu;
    P1 = P1pp; P2 = P2pp; b1 = b1pp; W2 = W2pp; b2 = b2pp;
    rp = rowptr + 12292; ent = entries + 458752;
    wout = w_pp; k0 = kpp0; k1 = kpp1;
  } else {
    row = blk - NPn; Ncols = NAn; shift = 16; mask = 0xFFFFu;
    P1 = P1aa; P2 = P2aa; b1 = b1aa; W2 = W2aa; b2 = b2aa;
    rp = rowptr + 16389; ent = entries + 589824;
    wout = w_aa; k0 = kaa0; k1 = kaa1;
  }
  P1s[tid] = P1[(size_t)row * 256 + tid];
  b1s[tid] = b1[tid];
  w2s[tid] = W2[tid * 2];
  if (tid == 0) candCnt = 0;
  for (int c = tid; c < Ncols; c += 256) ys[c] = 0.f;
  __syncthreads();
  float bias2 = b2[0];
  int beg = rp[row], end = rp[row + 1];
  int j = lane << 2;
  for (int k = beg + wv * 4; k < end; k += 16) {
    int n = end - k; if (n > 4) n = 4;
    unsigned pl0 = (unsigned)ent[k];
    unsigned pl1 = (n > 1) ? (unsigned)ent[k + 1] : pl0;
    unsigned pl2 = (n > 2) ? (unsigned)ent[k + 2] : pl0;
    unsigned pl3 = (n > 3) ? (unsigned)ent[k + 3] : pl0;
    int d0 = (int)(pl0 >> shift), d1 = (int)(pl1 >> shift);
    int d2 = (int)(pl2 >> shift), d3 = (int)(pl3 >> shift);
    float4 q0 = *(const float4*)&P2[(size_t)d0 * 256 + j];
    float4 q1 = *(const float4*)&P2[(size_t)d1 * 256 + j];
    float4 q2 = *(const float4*)&P2[(size_t)d2 * 256 + j];
    float4 q3 = *(const float4*)&P2[(size_t)d3 * 256 + j];
    float pa = P1s[j + 0], pb = P1s[j + 1], pc = P1s[j + 2], pd = P1s[j + 3];
    float ba = b1s[j + 0], bb = b1s[j + 1], bc_ = b1s[j + 2], bd = b1s[j + 3];
    float wa = w2s[j + 0], wb = w2s[j + 1], wc = w2s[j + 2], wd = w2s[j + 3];
    float s0 = fmaxf(pa + q0.x + ba, 0.f) * wa + fmaxf(pb + q0.y + bb, 0.f) * wb +
               fmaxf(pc + q0.z + bc_, 0.f) * wc + fmaxf(pd + q0.w + bd, 0.f) * wd;
    float s1 = fmaxf(pa + q1.x + ba, 0.f) * wa + fmaxf(pb + q1.y + bb, 0.f) * wb +
               fmaxf(pc + q1.z + bc_, 0.f) * wc + fmaxf(pd + q1.w + bd, 0.f) * wd;
    float s2 = fmaxf(pa + q2.x + ba, 0.f) * wa + fmaxf(pb + q2.y + bb, 0.f) * wb +
               fmaxf(pc + q2.z + bc_, 0.f) * wc + fmaxf(pd + q2.w + bd, 0.f) * wd;
    float s3 = fmaxf(pa + q3.x + ba, 0.f) * wa + fmaxf(pb + q3.y + bb, 0.f) * wb +
               fmaxf(pc + q3.z + bc_, 0.f) * wc + fmaxf(pd + q3.w + bd, 0.f) * wd;
    for (int off = 32; off; off >>= 1) {
      s0 += __shfl_down(s0, off);
      s1 += __shfl_down(s1, off);
      s2 += __shfl_down(s2, off);
      s3 += __shfl_down(s3, off);
    }
    if (lane == 0) {
      atomicAdd(&ys[d0], s0 + bias2);
      if (n > 1) atomicAdd(&ys[d1], s1 + bias2);
      if (n > 2) atomicAdd(&ys[d2], s2 + bias2);
      if (n > 3) atomicAdd(&ys[d3], s3 + bias2);
    }
  }
  __syncthreads();
  uint32_t rowbase = (uint32_t)row * (uint32_t)Ncols;
  for (int c = tid; c < Ncols; c += 256) {
    float a = ys[c];
    if (a > 0.f) {
      uint32_t x0 = 0u, x1 = rowbase + (uint32_t)c;
      tf2x32(k0, k1, x0, x1);
      uint32_t bits = x0 ^ x1;
      float fl = __uint_as_float((bits >> 9) | 0x3f800000u) - 1.0f;
      float u = fmaxf(1e-10f, fl + 1e-10f);
      float gn = -logf(-logf(u));
      float y = a + gn;  // tau == 1.0
      int pos = atomicAdd(&candCnt, 1);
      if (pos < 256) { scrF[pos] = y; scrI[pos] = c; }
    }
  }
  __syncthreads();
  int cnt = candCnt;
  if (cnt >= KSEL && cnt <= 256) {
    if (wv == 0) {
      int sreg[KSEL];
#pragma unroll
      for (int it = 0; it < KSEL; ++it) {
        float best = -3.4e38f; int bc = 0x7fffffff;
        for (int kk = lane; kk < cnt; kk += 64) {
          int c = scrI[kk];
          bool dead = false;
#pragma unroll
          for (int q = 0; q < KSEL; ++q) dead |= (q < it) && (c == sreg[q]);
          if (!dead) {
            float v = scrF[kk];
            if (v > best || (v == best && c < bc)) { best = v; bc = c; }
          }
        }
        for (int m = 32; m; m >>= 1) {
          float ov = __shfl_xor(best, m); int oc = __shfl_xor(bc, m);
          if (ov > best || (ov == best && oc < bc)) { best = ov; bc = oc; }
        }
        sreg[it] = bc;
        if (lane == 0) sel5[it] = bc;
      }
    }
  } else {
    for (int c = tid; c < Ncols; c += 256) {
      float a = ys[c];
      float y = -1e9f;
      if (a > 0.f) {
        uint32_t x0 = 0u, x1 = rowbase + (uint32_t)c;
        tf2x32(k0, k1, x0, x1);
        uint32_t bits = x0 ^ x1;
        float fl = __uint_as_float((bits >> 9) | 0x3f800000u) - 1.0f;
        float u = fmaxf(1e-10f, fl + 1e-10f);
        float gn = -logf(-logf(u));
        y = a + gn;
      }
      ys[c] = y;
    }
    __syncthreads();
    for (int it = 0; it < KSEL; ++it) {
      float best = -3.4e38f; int bcol = 0x7fffffff;
      for (int c = tid; c < Ncols; c += 256) {
        float v = ys[c];
        if (v > best) { best = v; bcol = c; }
      }
      scrF[tid] = best; scrI[tid] = bcol;
      __syncthreads();
      for (int s = 128; s; s >>= 1) {
        if (tid < s) {
          float v2 = scrF[tid + s]; int c2 = scrI[tid + s];
          if (v2 > scrF[tid] || (v2 == scrF[tid] && c2 < scrI[tid])) {
            scrF[tid] = v2; scrI[tid] = c2;
          }
        }
        __syncthreads();
      }
      if (tid == 0) {
        sel5[it] = scrI[0];
        ys[scrI[0]] = -3.0e38f;
      }
      __syncthreads();
    }
  }
  __syncthreads();
  for (int k = beg + tid; k < end; k += 256) {
    unsigned pl = (unsigned)ent[k];
    int d = (int)(pl >> shift);
    int e = (int)(pl & mask);
    float v = 0.f;
#pragma unroll
    for (int q = 0; q < KSEL; ++q) v = (sel5[q] == d) ? 1.f : v;
    wout[e] = v;
  }
}

}  // namespace

extern "C" void kernel_launch(void* const* d_in, const int* in_sizes, int n_in,
                              void* d_out, int out_size, void* d_ws, size_t ws_size,
                              hipStream_t stream)
{
  (void)in_sizes; (void)n_in; (void)out_size; (void)ws_size;
  const float* x_p = (const float*)d_in[0];
  const float* x_a = (const float*)d_in[1];
  const int* ei_pp = (const int*)d_in[2];
  const int* ei_aa = (const int*)d_in[3];
  const int* ei_pa = (const int*)d_in[4];
  const int* ei_ap = (const int*)d_in[5];
  const int* idxPtr = (const int*)d_in[8];
  const float* Wself_p0 = (const float*)d_in[9];
  const float* Wself_p1 = (const float*)d_in[10];
  const float* Wself_a0 = (const float*)d_in[11];
  const float* Wself_a1 = (const float*)d_in[12];
  const float* Wpp0 = (const float*)d_in[13]; const float* Wpp1 = (const float*)d_in[14];
  const float* Waa0 = (const float*)d_in[15]; const float* Waa1 = (const float*)d_in[16];
  const float* Wpa0 = (const float*)d_in[17]; /* Wpa1 unused: author L1 dropped */
  const float* Wap0 = (const float*)d_in[19]; const float* Wap1 = (const float*)d_in[20];
  const float* Wep1_pp = (const float*)d_in[21]; const float* bep1_pp = (const float*)d_in[22];
  const float* Wep2_pp = (const float*)d_in[23]; const float* bep2_pp = (const float*)d_in[24];
  const float* Wep1_aa = (const float*)d_in[25]; const float* bep1_aa = (const float*)d_in[26];
  const float* Wep2_aa = (const float*)d_in[27]; const float* bep2_aa = (const float*)d_in[28];
  const float* Wc = (const float*)d_in[29]; const float* bc = (const float*)d_in[30];

  float* out = (float*)d_out;
  float* w_pp_out = out + 5;
  float* w_aa_out = out + 5 + EPPc;

  const int* src_pp = ei_pp;  const int* dst_pp = ei_pp + EPPc;
  const int* src_aa = ei_aa;  const int* dst_aa = ei_aa + EAAc;
  const int* src_pa = ei_pa;  const int* dst_pa = ei_pa + 131072;
  const int* src_ap = ei_ap;  const int* dst_ap = ei_ap + 131072;

  // ---- workspace layout (bump allocator; gctr+cnt first: contiguous memset region) ----
  char* p = (char*)d_ws;
  auto alloc = [&](size_t bytes) -> void* {
    void* r = (void*)p;
    p += (bytes + 255) & ~(size_t)255;
    return r;
  };
  int* gctr    = (int*)alloc(64 * sizeof(int));        // barrier counters (256 B)
  int* cnt     = (int*)alloc(18432 * sizeof(int));
  int* rowptr  = (int*)alloc(18438 * sizeof(int));
  int* cursor  = (int*)alloc(18432 * sizeof(int));
  int* entries = (int*)alloc(655360 * sizeof(int));
  float* Mpp  = (float*)alloc((size_t)NPn * Hh * sizeof(float));
  float* Maa  = (float*)alloc((size_t)NAn * Hh * sizeof(float));
  float* Mpa  = (float*)alloc((size_t)NAn * Hh * sizeof(float));
  float* Map  = (float*)alloc((size_t)NPn * Hh * sizeof(float));
  float* h1p0 = (float*)alloc((size_t)NPn * Hh * sizeof(float));
  float* h1a0 = (float*)alloc((size_t)NAn * Hh * sizeof(float));
  float* h1p1 = (float*)alloc((size_t)NPn * Hh * sizeof(float));
  float* h1a1 = (float*)alloc((size_t)NAn * Hh * sizeof(float));
  float* h2p0 = (float*)alloc((size_t)NPn * Hh * sizeof(float));
  float* h2a0 = (float*)alloc((size_t)NAn * Hh * sizeof(float));
  float* P1pp = (float*)alloc((size_t)NPn * 256 * sizeof(float));
  float* P2pp = (float*)alloc((size_t)NPn * 256 * sizeof(float));
  float* P1aa = (float*)alloc((size_t)NAn * 256 * sizeof(float));
  float* P2aa = (float*)alloc((size_t)NAn * 256 * sizeof(float));

  const int RP_PPD = 0, RP_AAD = 4097, RP_PAD = 6146, RP_APD = 8195;
  const int EN_PPD = 0, EN_AAD = 131072, EN_PAD = 196608, EN_APD = 327680;

  // zero barrier counters + cnt in one contiguous memset (gctr 256 B + cnt 73728 B)
  hipMemsetAsync(gctr, 0, 256 + 18432 * sizeof(int), stream);

  // ---- mega1: CSR build + GNN1 + edge-MLP projections ----
  Mega1Args m1{};
  m1.spp = src_pp; m1.dpp = dst_pp; m1.saa = src_aa; m1.daa = dst_aa;
  m1.spa = src_pa; m1.dpa = dst_pa; m1.sap = src_ap; m1.dap = dst_ap;
  m1.cnt = cnt; m1.rowptr = rowptr; m1.cursor = cursor; m1.entries = entries;
  m1.gctr = gctr;
  m1.agg1.s[0] = {x_p, nullptr, Mpp, RP_PPD, EN_PPD, 18};
  m1.agg1.s[1] = {x_a, nullptr, Maa, RP_AAD, EN_AAD, 16};
  m1.agg1.start[0] = 0; m1.agg1.start[1] = NPn; m1.agg1.start[2] = NPn + NAn;
  m1.agg1.nseg = 2;
  m1.gemm1.d[0] = {x_p, Wself_p0, Mpp, Wpp0, nullptr, nullptr, h1p0, NPn, 128, 2, 1};
  m1.gemm1.d[1] = {x_a, Wself_a0, Maa, Waa0, nullptr, nullptr, h1a0, NAn, 128, 2, 1};
  m1.gemm1.bstart[0] = 0; m1.gemm1.bstart[1] = 128; m1.gemm1.bstart[2] = 192;
  m1.gemm1.nd = 2;
  m1.agg2.s[0] = {h1p0, nullptr, Mpp, RP_PPD, EN_PPD, 18};
  m1.agg2.s[1] = {h1a0, nullptr, Maa, RP_AAD, EN_AAD, 16};
  m1.agg2.start[0] = 0; m1.agg2.start[1] = NPn; m1.agg2.start[2] = NPn + NAn;
  m1.agg2.nseg = 2;
  m1.gemm2.d[0] = {h1p0, Wself_p1, Mpp, Wpp1, nullptr, nullptr, h1p1, NPn, 128, 2, 1};
  m1.gemm2.d[1] = {h1a0, Wself_a1, Maa, Waa1, nullptr, nullptr, h1a1, NAn, 128, 2, 1};
  m1.gemm2.bstart[0] = 0; m1.gemm2.bstart[1] = 128; m1.gemm2.bstart[2] = 192;
  m1.gemm2.nd = 2;
  m1.gemmP.d[0] = {h1p1, Wep1_pp,             nullptr, nullptr, nullptr, nullptr, P1pp, NPn, 256, 1, 0};
  m1.gemmP.d[1] = {h1p1, Wep1_pp + 128 * 256, nullptr, nullptr, nullptr, nullptr, P2pp, NPn, 256, 1, 0};
  m1.gemmP.d[2] = {h1a1, Wep1_aa,             nullptr, nullptr, nullptr, nullptr, P1aa, NAn, 256, 1, 0};
  m1.gemmP.d[3] = {h1a1, Wep1_aa + 128 * 256, nullptr, nullptr, nullptr, nullptr, P2aa, NAn, 256, 1, 0};
  m1.gemmP.bstart[0] = 0; m1.gemmP.bstart[1] = 256; m1.gemmP.bstart[2] = 512;
  m1.gemmP.bstart[3] = 640; m1.gemmP.bstart[4] = 768; m1.gemmP.nd = 4;
  mega1<<<GRID, 256, 0, stream>>>(m1);

  // ---- JAX keys: key(42) -> split -> (kpp, kaa) (partitionable fold-in) ----
  uint32_t kpp0, kpp1, kaa0, kaa1;
  { uint32_t a0 = 0, a1 = 0; tf2x32(0u, 42u, a0, a1); kpp0 = a0; kpp1 = a1; }
  { uint32_t a0 = 0, a1 = 1; tf2x32(0u, 42u, a0, a1); kaa0 = a0; kaa1 = a1; }

  // ---- fused edge-pred + coalesce + gumbel top-5 + w write (standalone: occupancy) ----
  row_topk<<<NPn + NAn, 256, 0, stream>>>(P1pp, P2pp, bep1_pp, Wep2_pp, bep2_pp,
                                          P1aa, P2aa, bep1_aa, Wep2_aa, bep2_aa,
                                          rowptr, entries, w_pp_out, w_aa_out,
                                          kpp0, kpp1, kaa0, kaa1);

  // ---- mega2: GNN2 layer 0 + fused layer-1/classifier ----
  Mega2Args m2{};
  m2.rowptr = rowptr; m2.entries = entries; m2.gctr = gctr;
  m2.agg3.s[0] = {x_p, w_pp_out, Mpp, RP_PPD, EN_PPD, 18};
  m2.agg3.s[1] = {x_a, nullptr,  Map, RP_APD, EN_APD, 0};
  m2.agg3.s[2] = {x_a, w_aa_out, Maa, RP_AAD, EN_AAD, 16};
  m2.agg3.s[3] = {x_p, nullptr,  Mpa, RP_PAD, EN_PAD, 0};
  m2.agg3.start[0] = 0; m2.agg3.start[1] = NPn; m2.agg3.start[2] = 2 * NPn;
  m2.agg3.start[3] = 2 * NPn + NAn; m2.agg3.start[4] = 2 * NPn + 2 * NAn;
  m2.agg3.nseg = 4;
  m2.gemm3.d[0] = {x_p, Wself_p0, Mpp, Wpp0, Map, Wap0, h2p0, NPn, 128, 3, 1};
  m2.gemm3.d[1] = {x_a, Wself_a0, Maa, Waa0, Mpa, Wpa0, h2a0, NAn, 128, 3, 1};
  m2.gemm3.bstart[0] = 0; m2.gemm3.bstart[1] = 128; m2.gemm3.bstart[2] = 192;
  m2.gemm3.nd = 2;
  m2.hp = h2p0; m2.ha = h2a0; m2.wpp = w_pp_out;
  m2.Wself = Wself_p1; m2.Wpp = Wpp1; m2.Wap = Wap1; m2.Wc = Wc; m2.bc = bc;
  m2.idxPtr = idxPtr; m2.out = out;
  mega2<<<GRID, 256, 0, stream>>>(m2);
}

// Round 6
// 398.628 us; speedup vs baseline: 4.4981x; 4.4981x over previous
//
#include <hip/hip_runtime.h>
#include <stdint.h>

// ---------------------------------------------------------------------------
// MultiGraph hetero-GNN + gumbel-top-k edge pruning, fp32 throughout.
// Round 6: revert r5's megakernels (threadfence L2-flush thrash: FETCH 565MB,
// 4.3x regression). Base = r4 (421us). New: sparse row_topk (no dense ys[4096];
// per-row candidate dedupe in wave 0, deg<=128 guaranteed by Poisson-32 tail),
// chunk-8 MLP in unweighted aggs (k-ascending adds preserved = bit-exact).
// PRNG: JAX threefry2x32, partitionable path (verified absmax=0.0 r1-r5).
// ---------------------------------------------------------------------------

namespace {

constexpr int NPn = 4096;
constexpr int NAn = 2048;
constexpr int Hh  = 128;
constexpr int EPPc = 131072;
constexpr int EAAc = 65536;
constexpr int KSEL = 5;

// CSR segments: 0 pp-dst, 1 aa-dst, 2 pa-dst, 3 ap-dst, 4 pp-src, 5 aa-src
// rowptr offsets: 0, 4097, 6146, 8195, 12292, 16389 (each N+1)
// entry offsets:  0, 131072, 196608, 327680, 458752, 589824 (total 655360)
// payloads: pp: (other<<18)|e  aa: (other<<16)|e  pa/ap: src only

__host__ __device__ static inline void tf2x32(uint32_t k0, uint32_t k1,
                                              uint32_t& x0, uint32_t& x1) {
  uint32_t ks2 = k0 ^ k1 ^ 0x1BD11BDAu;
  x0 += k0; x1 += k1;
#define TF_R(r) { x0 += x1; x1 = (x1 << (r)) | (x1 >> (32 - (r))); x1 ^= x0; }
  TF_R(13) TF_R(15) TF_R(26) TF_R(6)
  x0 += k1;  x1 += ks2 + 1u;
  TF_R(17) TF_R(29) TF_R(16) TF_R(24)
  x0 += ks2; x1 += k0 + 2u;
  TF_R(13) TF_R(15) TF_R(26) TF_R(6)
  x0 += k0;  x1 += k1 + 3u;
  TF_R(17) TF_R(29) TF_R(16) TF_R(24)
  x0 += k1;  x1 += ks2 + 4u;
  TF_R(13) TF_R(15) TF_R(26) TF_R(6)
  x0 += ks2; x1 += k0 + 5u;
#undef TF_R
}

// ---------------- CSR build (r4 verbatim) ----------------
__global__ __launch_bounds__(256) void hist_kernel(
    const int* d0, const int* d1, const int* d2, const int* d3,
    const int* d4, const int* d5, int* cnt)
{
  int i = blockIdx.x * 256 + threadIdx.x;
  const int* kp; int co, e;
  if      (i < 131072) { kp = d0; co = 0;     e = i; }
  else if (i < 196608) { kp = d1; co = 4096;  e = i - 131072; }
  else if (i < 327680) { kp = d2; co = 6144;  e = i - 196608; }
  else if (i < 458752) { kp = d3; co = 8192;  e = i - 327680; }
  else if (i < 589824) { kp = d4; co = 12288; e = i - 458752; }
  else if (i < 655360) { kp = d5; co = 16384; e = i - 589824; }
  else return;
  atomicAdd(&cnt[co + kp[e]], 1);
}

__global__ __launch_bounds__(256) void scan_kernel(const int* cnt, int* rowptr, int* cursor)
{
  __shared__ int wsum[4];
  const int Ns[6]   = {4096, 2048, 2048, 4096, 4096, 2048};
  const int coff[6] = {0, 4096, 6144, 8192, 12288, 16384};
  const int roff[6] = {0, 4097, 6146, 8195, 12292, 16389};
  int rel = blockIdx.x, tid = threadIdx.x;
  int N = Ns[rel], co = coff[rel], ro = roff[rel];
  int per = N >> 8;                 // 16 or 8
  int base = tid * per;
  int local[16];
  int s = 0;
  for (int i = 0; i < per; ++i) { local[i] = s; s += cnt[co + base + i]; }
  int lane = tid & 63, wv = tid >> 6;
  int x = s;
  for (int d = 1; d < 64; d <<= 1) {
    int y = __shfl_up(x, d);
    if (lane >= d) x += y;
  }
  if (lane == 63) wsum[wv] = x;
  __syncthreads();
  int woff = 0;
  for (int q = 0; q < wv; ++q) woff += wsum[q];
  int excl = woff + x - s;
  for (int i = 0; i < per; ++i) {
    int v = excl + local[i];
    rowptr[ro + base + i] = v;
    cursor[co + base + i] = v;
  }
  if (tid == 255) rowptr[ro + N] = excl + s;
}

__global__ __launch_bounds__(256) void scatter_kernel(
    const int* src_pp, const int* dst_pp, const int* src_aa, const int* dst_aa,
    const int* src_pa, const int* dst_pa, const int* src_ap, const int* dst_ap,
    int* cursor, int* entries)
{
  int i = blockIdx.x * 256 + threadIdx.x;
  int key, pl, co, eo;
  if (i < 131072) {                       // pp by dst
    int e = i;
    key = dst_pp[e]; pl = (src_pp[e] << 18) | e; co = 0; eo = 0;
  } else if (i < 196608) {                // aa by dst
    int e = i - 131072;
    key = dst_aa[e]; pl = (src_aa[e] << 16) | e; co = 4096; eo = 131072;
  } else if (i < 327680) {                // pa by dst (payload = src paper)
    int e = i - 196608;
    key = dst_pa[e]; pl = src_pa[e]; co = 6144; eo = 196608;
  } else if (i < 458752) {                // ap by dst (payload = src author)
    int e = i - 327680;
    key = dst_ap[e]; pl = src_ap[e]; co = 8192; eo = 327680;
  } else if (i < 589824) {                // pp by src (payload = (dst<<18)|e)
    int e = i - 458752;
    key = src_pp[e]; pl = (dst_pp[e] << 18) | e; co = 12288; eo = 458752;
  } else if (i < 655360) {                // aa by src
    int e = i - 589824;
    key = src_aa[e]; pl = (dst_aa[e] << 16) | e; co = 16384; eo = 589824;
  } else return;
  int pos = atomicAdd(&cursor[co + key], 1);
  entries[eo + pos] = pl;
}

// ---------------- batched mean aggregation --------------------------------------------
// 2 nodes per wave: half-wave (32 lanes) per node, lane covers 4 floats (float4).
// Chunk-8 load batching (unweighted): 8 independent gathers in flight; adds stay
// k-ascending (summation order identical to r2-r4 -> bit-exact).
struct AggSeg { const float* h; const float* w; float* M; int rpOff; int enOff; int shift; };
struct AggArgs { AggSeg s[4]; int start[5]; int nseg; };

__global__ __launch_bounds__(256) void multi_agg(AggArgs a, const int* __restrict__ rowptr,
                                                 const int* __restrict__ entries)
{
  int g = blockIdx.x * 8 + (threadIdx.x >> 5);   // 8 half-waves = 8 nodes per block
  int fl = (threadIdx.x & 31) << 2;              // float4 feature offset
  if (g >= a.start[a.nseg]) return;
  int si = 0;
  while (si < a.nseg - 1 && g >= a.start[si + 1]) ++si;
  AggSeg sg = a.s[si];
  int node = g - a.start[si];
  const int* rp = rowptr + sg.rpOff;
  const int* ent = entries + sg.enOff;
  int b = rp[node], e = rp[node + 1];
  const float* h = sg.h;
  int sh = sg.shift;
  float ax = 0.f, ay = 0.f, az = 0.f, aw = 0.f;
  if (sg.w) {
    unsigned mask = (1u << sh) - 1u;
    int k = b;
    for (; k + 3 < e; k += 4) {
      unsigned p0 = (unsigned)ent[k], p1 = (unsigned)ent[k + 1];
      unsigned p2 = (unsigned)ent[k + 2], p3 = (unsigned)ent[k + 3];
      float w0 = sg.w[p0 & mask], w1 = sg.w[p1 & mask];
      float w2v = sg.w[p2 & mask], w3 = sg.w[p3 & mask];
      float4 v0, v1, v2, v3;
      if (w0 != 0.f) v0 = *(const float4*)&h[(size_t)(p0 >> sh) * Hh + fl];
      if (w1 != 0.f) v1 = *(const float4*)&h[(size_t)(p1 >> sh) * Hh + fl];
      if (w2v != 0.f) v2 = *(const float4*)&h[(size_t)(p2 >> sh) * Hh + fl];
      if (w3 != 0.f) v3 = *(const float4*)&h[(size_t)(p3 >> sh) * Hh + fl];
      if (w0 != 0.f) { ax += v0.x; ay += v0.y; az += v0.z; aw += v0.w; }
      if (w1 != 0.f) { ax += v1.x; ay += v1.y; az += v1.z; aw += v1.w; }
      if (w2v != 0.f) { ax += v2.x; ay += v2.y; az += v2.z; aw += v2.w; }
      if (w3 != 0.f) { ax += v3.x; ay += v3.y; az += v3.z; aw += v3.w; }
    }
    for (; k < e; ++k) {
      unsigned pl = (unsigned)ent[k];
      float wt = sg.w[pl & mask];
      if (wt != 0.f) {
        float4 v = *(const float4*)&h[(size_t)(pl >> sh) * Hh + fl];
        ax += v.x; ay += v.y; az += v.z; aw += v.w;
      }
    }
  } else {
    int k = b;
    for (; k + 7 < e; k += 8) {
      unsigned p0 = (unsigned)ent[k],     p1 = (unsigned)ent[k + 1];
      unsigned p2 = (unsigned)ent[k + 2], p3 = (unsigned)ent[k + 3];
      unsigned p4 = (unsigned)ent[k + 4], p5 = (unsigned)ent[k + 5];
      unsigned p6 = (unsigned)ent[k + 6], p7 = (unsigned)ent[k + 7];
      float4 v0 = *(const float4*)&h[(size_t)(p0 >> sh) * Hh + fl];
      float4 v1 = *(const float4*)&h[(size_t)(p1 >> sh) * Hh + fl];
      float4 v2 = *(const float4*)&h[(size_t)(p2 >> sh) * Hh + fl];
      float4 v3 = *(const float4*)&h[(size_t)(p3 >> sh) * Hh + fl];
      float4 v4 = *(const float4*)&h[(size_t)(p4 >> sh) * Hh + fl];
      float4 v5 = *(const float4*)&h[(size_t)(p5 >> sh) * Hh + fl];
      float4 v6 = *(const float4*)&h[(size_t)(p6 >> sh) * Hh + fl];
      float4 v7 = *(const float4*)&h[(size_t)(p7 >> sh) * Hh + fl];
      ax += v0.x; ay += v0.y; az += v0.z; aw += v0.w;
      ax += v1.x; ay += v1.y; az += v1.z; aw += v1.w;
      ax += v2.x; ay += v2.y; az += v2.z; aw += v2.w;
      ax += v3.x; ay += v3.y; az += v3.z; aw += v3.w;
      ax += v4.x; ay += v4.y; az += v4.z; aw += v4.w;
      ax += v5.x; ay += v5.y; az += v5.z; aw += v5.w;
      ax += v6.x; ay += v6.y; az += v6.z; aw += v6.w;
      ax += v7.x; ay += v7.y; az += v7.z; aw += v7.w;
    }
    for (; k < e; ++k) {
      unsigned pl = (unsigned)ent[k];
      float4 v = *(const float4*)&h[(size_t)(pl >> sh) * Hh + fl];
      ax += v.x; ay += v.y; az += v.z; aw += v.w;
    }
  }
  float cd = fmaxf((float)(e - b), 1.0f);
  float4 o; o.x = ax / cd; o.y = ay / cd; o.z = az / cd; o.w = aw / cd;
  *(float4*)&sg.M[(size_t)node * Hh + fl] = o;
}

// ---------------- batched multi-part fp32 GEMM (r4 dbuf verbatim) ----------------------
struct GDesc {
  const float* A0; const float* W0; const float* A1; const float* W1;
  const float* A2; const float* W2; float* C; int M; int N; int parts; int relu;
};
struct GArgs { GDesc d[4]; int bstart[5]; int nd; };

__global__ __launch_bounds__(256) void gemm_b(GArgs g)
{
  __shared__ __align__(16) float As[2][32][68];  // [buf][k][m]
  __shared__ __align__(16) float Ws[2][32][68];  // [buf][k][n]
  int blk = blockIdx.x;
  int di = 0;
  while (di < g.nd - 1 && blk >= g.bstart[di + 1]) ++di;
  GDesc D = g.d[di];
  int local = blk - g.bstart[di];
  int nTiles = D.N >> 6;
  int bx = local % nTiles;
  int by = local / nTiles;
  int m0 = by << 6, n0 = bx << 6;
  int N = D.N;
  int tid = threadIdx.x;
  int tr = tid >> 4, tc = tid & 15;
  int r = tid >> 3, f = tid & 7;
  float acc[4][4] = {{0.f}};
  const float* Ap[3] = {D.A0, D.A1, D.A2};
  const float* Wp[3] = {D.W0, D.W1, D.W2};
  int T = D.parts << 2;            // chunks: part-major, k0 = (t&3)*32

  float4 va0, va1, vw0, vw1;
  auto ldchunk = [&](int t) {
    const float* A = Ap[t >> 2]; const float* W = Wp[t >> 2];
    int k0 = (t & 3) << 5;
    va0 = *(const float4*)&A[(size_t)(m0 + r) * 128 + k0 + f * 4];
    va1 = *(const float4*)&A[(size_t)(m0 + r + 32) * 128 + k0 + f * 4];
    vw0 = *(const float4*)&W[(size_t)(k0 + r) * N + n0 + f * 4];
    vw1 = *(const float4*)&W[(size_t)(k0 + r) * N + n0 + f * 4 + 32];
  };
  auto stchunk = [&](int buf) {
    As[buf][f * 4 + 0][r] = va0.x; As[buf][f * 4 + 1][r] = va0.y;
    As[buf][f * 4 + 2][r] = va0.z; As[buf][f * 4 + 3][r] = va0.w;
    As[buf][f * 4 + 0][r + 32] = va1.x; As[buf][f * 4 + 1][r + 32] = va1.y;
    As[buf][f * 4 + 2][r + 32] = va1.z; As[buf][f * 4 + 3][r + 32] = va1.w;
    *(float4*)&Ws[buf][r][f * 4] = vw0;
    *(float4*)&Ws[buf][r][f * 4 + 32] = vw1;
  };

  ldchunk(0);
  stchunk(0);
  __syncthreads();
  for (int t = 0; t < T; ++t) {
    int cur = t & 1;
    bool more = (t + 1 < T);
    if (more) ldchunk(t + 1);      // global loads in flight during compute
#pragma unroll
    for (int k = 0; k < 32; ++k) {
      float4 a = *(const float4*)&As[cur][k][tr * 4];
      float4 b = *(const float4*)&Ws[cur][k][tc * 4];
      acc[0][0] += a.x * b.x; acc[0][1] += a.x * b.y; acc[0][2] += a.x * b.z; acc[0][3] += a.x * b.w;
      acc[1][0] += a.y * b.x; acc[1][1] += a.y * b.y; acc[1][2] += a.y * b.z; acc[1][3] += a.y * b.w;
      acc[2][0] += a.z * b.x; acc[2][1] += a.z * b.y; acc[2][2] += a.z * b.z; acc[2][3] += a.z * b.w;
      acc[3][0] += a.w * b.x; acc[3][1] += a.w * b.y; acc[3][2] += a.w * b.z; acc[3][3] += a.w * b.w;
    }
    if (more) stchunk(cur ^ 1);
    __syncthreads();
  }
#pragma unroll
  for (int i = 0; i < 4; ++i) {
    float4 v;
    v.x = acc[i][0]; v.y = acc[i][1]; v.z = acc[i][2]; v.w = acc[i][3];
    if (D.relu) {
      v.x = fmaxf(v.x, 0.f); v.y = fmaxf(v.y, 0.f);
      v.z = fmaxf(v.z, 0.f); v.w = fmaxf(v.w, 0.f);
    }
    *(float4*)&D.C[(size_t)(m0 + tr * 4 + i) * N + n0 + tc * 4] = v;
  }
}

// ---------------- fused edge-MLP + sparse coalesce + masked gumbel top-5 + w write ------
// One block per src row. Edge phase identical to r4 (bit-exact preds, 4-edge ILP,
// same 6-step shfl tree), but results stored to LDS slots by CSR index (no dense
// ys[4096]). Wave 0 dedupes (ascending-slot sums), computes gumbel at A>0 leaders,
// runs 5 shuffle-argmax passes. deg <= 128 guaranteed (Poisson-32, e^-85 tail).
__global__ __launch_bounds__(256) void row_topk(
    const float* __restrict__ P1pp, const float* __restrict__ P2pp,
    const float* __restrict__ b1pp, const float* __restrict__ W2pp,
    const float* __restrict__ b2pp,
    const float* __restrict__ P1aa, const float* __restrict__ P2aa,
    const float* __restrict__ b1aa, const float* __restrict__ W2aa,
    const float* __restrict__ b2aa,
    const int* __restrict__ rowptr, const int* __restrict__ entries,
    float* __restrict__ w_pp, float* __restrict__ w_aa,
    uint32_t kpp0, uint32_t kpp1, uint32_t kaa0, uint32_t kaa1)
{
  __shared__ float P1s[256], b1s[256], w2s[256];
  __shared__ int   dS[128];
  __shared__ float pS[128];
  __shared__ int   sel5[KSEL];
  int blk = blockIdx.x, tid = threadIdx.x;
  int lane = tid & 63, wv = tid >> 6;
  int row, Ncols, shift; unsigned mask;
  const float* P1; const float* P2; const float* b1; const float* W2; const float* b2;
  const int* rp; const int* ent; float* wout; uint32_t k0, k1;
  if (blk < NPn) {
    row = blk; Ncols = NPn; shift = 18; mask = 0x3FFFFu;
    P1 = P1pp; P2 = P2pp; b1 = b1pp; W2 = W2pp; b2 = b2pp;
    rp = rowptr + 12292; ent = entries + 458752;
    wout = w_pp; k0 = kpp0; k1 = kpp1;
  } else {
    row = blk - NPn; Ncols = NAn; shift = 16; mask = 0xFFFFu;
    P1 = P1aa; P2 = P2aa; b1 = b1aa; W2 = W2aa; b2 = b2aa;
    rp = rowptr + 16389; ent = entries + 589824;
    wout = w_aa; k0 = kaa0; k1 = kaa1;
  }
  P1s[tid] = P1[(size_t)row * 256 + tid];
  b1s[tid] = b1[tid];
  w2s[tid] = W2[tid * 2];
  __syncthreads();
  float bias2 = b2[0];
  int beg = rp[row], end = rp[row + 1];
  int deg = end - beg;
  // --- edge phase: 4 edges per wave, r4-identical arithmetic; lane0 -> LDS slots ---
  int j = lane << 2;
  for (int k = beg + wv * 4; k < end; k += 16) {
    int n = end - k; if (n > 4) n = 4;
    unsigned pl0 = (unsigned)ent[k];
    unsigned pl1 = (n > 1) ? (unsigned)ent[k + 1] : pl0;
    unsigned pl2 = (n > 2) ? (unsigned)ent[k + 2] : pl0;
    unsigned pl3 = (n > 3) ? (unsigned)ent[k + 3] : pl0;
    int d0 = (int)(pl0 >> shift), d1 = (int)(pl1 >> shift);
    int d2 = (int)(pl2 >> shift), d3 = (int)(pl3 >> shift);
    float4 q0 = *(const float4*)&P2[(size_t)d0 * 256 + j];
    float4 q1 = *(const float4*)&P2[(size_t)d1 * 256 + j];
    float4 q2 = *(const float4*)&P2[(size_t)d2 * 256 + j];
    float4 q3 = *(const float4*)&P2[(size_t)d3 * 256 + j];
    float pa = P1s[j + 0], pb = P1s[j + 1], pc = P1s[j + 2], pd = P1s[j + 3];
    float ba = b1s[j + 0], bb = b1s[j + 1], bc_ = b1s[j + 2], bd = b1s[j + 3];
    float wa = w2s[j + 0], wb = w2s[j + 1], wc = w2s[j + 2], wd = w2s[j + 3];
    float s0 = fmaxf(pa + q0.x + ba, 0.f) * wa + fmaxf(pb + q0.y + bb, 0.f) * wb +
               fmaxf(pc + q0.z + bc_, 0.f) * wc + fmaxf(pd + q0.w + bd, 0.f) * wd;
    float s1 = fmaxf(pa + q1.x + ba, 0.f) * wa + fmaxf(pb + q1.y + bb, 0.f) * wb +
               fmaxf(pc + q1.z + bc_, 0.f) * wc + fmaxf(pd + q1.w + bd, 0.f) * wd;
    float s2 = fmaxf(pa + q2.x + ba, 0.f) * wa + fmaxf(pb + q2.y + bb, 0.f) * wb +
               fmaxf(pc + q2.z + bc_, 0.f) * wc + fmaxf(pd + q2.w + bd, 0.f) * wd;
    float s3 = fmaxf(pa + q3.x + ba, 0.f) * wa + fmaxf(pb + q3.y + bb, 0.f) * wb +
               fmaxf(pc + q3.z + bc_, 0.f) * wc + fmaxf(pd + q3.w + bd, 0.f) * wd;
    for (int off = 32; off; off >>= 1) {
      s0 += __shfl_down(s0, off);
      s1 += __shfl_down(s1, off);
      s2 += __shfl_down(s2, off);
      s3 += __shfl_down(s3, off);
    }
    if (lane == 0) {
      int base = k - beg;
      dS[base] = d0; pS[base] = s0 + bias2;
      if (n > 1) { dS[base + 1] = d1; pS[base + 1] = s1 + bias2; }
      if (n > 2) { dS[base + 2] = d2; pS[base + 2] = s2 + bias2; }
      if (n > 3) { dS[base + 3] = d3; pS[base + 3] = s3 + bias2; }
    }
  }
  __syncthreads();
  if (deg > 0 && wv == 0) {
    // --- dedupe (ascending-slot sums) + gumbel + top-5, all in wave 0 ---
    int   e0 = (lane < deg) ? dS[lane] : -1;
    float q0v = (lane < deg) ? pS[lane] : 0.f;
    bool  two = (deg > 64);
    int   e1 = -1; float q1v = 0.f;
    if (two && 64 + lane < deg) { e1 = dS[64 + lane]; q1v = pS[64 + lane]; }
    float a0 = 0.f, a1 = 0.f;
    bool lead0 = (e0 >= 0), lead1 = (e1 >= 0);
    for (int j2 = 0; j2 < deg; ++j2) {
      int bj; float bp;
      if (j2 < 64) { bj = __shfl(e0, j2); bp = __shfl(q0v, j2); }
      else         { bj = __shfl(e1, j2 - 64); bp = __shfl(q1v, j2 - 64); }
      if (e0 >= 0 && bj == e0) { a0 += bp; if (j2 < lane) lead0 = false; }
      if (e1 >= 0 && bj == e1) { a1 += bp; if (j2 < 64 + lane) lead1 = false; }
    }
    uint32_t rowbase = (uint32_t)row * (uint32_t)Ncols;
    float y0 = -1e9f, y1 = -1e9f;
    bool c0 = lead0 && (a0 > 0.f);
    if (c0) {
      uint32_t x0 = 0u, x1 = rowbase + (uint32_t)e0;
      tf2x32(k0, k1, x0, x1);
      uint32_t bits = x0 ^ x1;
      float fv = __uint_as_float((bits >> 9) | 0x3f800000u) - 1.0f;
      float u = fmaxf(1e-10f, fv + 1e-10f);
      y0 = a0 + (-logf(-logf(u)));
    }
    bool c1 = lead1 && (a1 > 0.f);
    if (c1) {
      uint32_t x0 = 0u, x1 = rowbase + (uint32_t)e1;
      tf2x32(k0, k1, x0, x1);
      uint32_t bits = x0 ^ x1;
      float fv = __uint_as_float((bits >> 9) | 0x3f800000u) - 1.0f;
      float u = fmaxf(1e-10f, fv + 1e-10f);
      y1 = a1 + (-logf(-logf(u)));
    }
    int cnt = __popcll(__ballot(c0)) + __popcll(__ballot(c1));
    int nsel = cnt < KSEL ? cnt : KSEL;
    for (int it = 0; it < nsel; ++it) {
      float best; int bc;
      if (y1 > y0 || (y1 == y0 && (unsigned)e1 < (unsigned)e0)) { best = y1; bc = e1; }
      else { best = y0; bc = e0; }
      for (int m = 32; m; m >>= 1) {
        float ov = __shfl_xor(best, m); int oc = __shfl_xor(bc, m);
        if (ov > best || (ov == best && (unsigned)oc < (unsigned)bc)) { best = ov; bc = oc; }
      }
      if (lane == 0) sel5[it] = bc;
      if (e0 == bc) y0 = -3.0e38f;
      if (e1 == bc) y1 = -3.0e38f;
    }
    if (nsel < KSEL && lane == 0) {
      // fill remaining with smallest column indices not yet selected
      // (matches dense tie-break over the all -1e9 masked cells)
      int c = 0;
      for (int it = nsel; it < KSEL; ++it) {
        for (;;) {
          bool used = false;
          for (int q = 0; q < it; ++q) used |= (sel5[q] == c);
          if (!used) break;
          ++c;
        }
        sel5[it] = c++;
      }
    }
  }
  __syncthreads();
  // --- write hard 0/1 weights onto this row's edges ---
  for (int k = beg + tid; k < end; k += 256) {
    unsigned pl = (unsigned)ent[k];
    int d = (int)(pl >> shift);
    int e = (int)(pl & mask);
    float v = 0.f;
#pragma unroll
    for (int q = 0; q < KSEL; ++q) v = (sel5[q] == d) ? 1.f : v;
    wout[e] = v;
  }
}

// ---------------- fused GNN2-layer1 (single row) + classifier (r4 verbatim) -------------
__global__ __launch_bounds__(128) void final_kernel(
    const float* __restrict__ hp, const float* __restrict__ ha,
    const int* __restrict__ idxPtr, const float* __restrict__ wpp,
    const int* __restrict__ rp_ppd, const int* __restrict__ ent_ppd,
    const int* __restrict__ rp_apd, const int* __restrict__ ent_apd,
    const float* __restrict__ Wself, const float* __restrict__ Wpp,
    const float* __restrict__ Wap,
    const float* __restrict__ Wc, const float* __restrict__ bc,
    float* __restrict__ out)
{
  __shared__ float selfr[128], mpp[128], mapr[128], t[128];
  int tid = threadIdx.x;
  int idx = idxPtr[0];
  selfr[tid] = hp[(size_t)idx * 128 + tid];
  {
    int b = rp_ppd[idx], e2 = rp_ppd[idx + 1];
    float acc = 0.f;
    for (int k = b; k < e2; ++k) {
      unsigned pl = (unsigned)ent_ppd[k];
      int s = (int)(pl >> 18);
      int e = (int)(pl & 0x3FFFFu);
      acc += wpp[e] * hp[(size_t)s * 128 + tid];
    }
    mpp[tid] = acc / fmaxf((float)(e2 - b), 1.0f);
  }
  {
    int b = rp_apd[idx], e2 = rp_apd[idx + 1];
    float acc = 0.f;
    for (int k = b; k < e2; ++k) {
      int s = ent_apd[k];
      acc += ha[(size_t)s * 128 + tid];
    }
    mapr[tid] = acc / fmaxf((float)(e2 - b), 1.0f);
  }
  __syncthreads();
  float s = 0.f;
  for (int m = 0; m < 128; ++m) {
    s += selfr[m] * Wself[m * 128 + tid] + mpp[m] * Wpp[m * 128 + tid] +
         mapr[m] * Wap[m * 128 + tid];
  }
  t[tid] = fmaxf(s, 0.f);
  __syncthreads();
  if (tid < 5) {
    float y = bc[tid];
    for (int k = 0; k < 128; ++k) y += t[k] * Wc[k * 5 + tid];
    out[tid] = y;
  }
}

}  // namespace

extern "C" void kernel_launch(void* const* d_in, const int* in_sizes, int n_in,
                              void* d_out, int out_size, void* d_ws, size_t ws_size,
                              hipStream_t stream)
{
  (void)in_sizes; (void)n_in; (void)out_size; (void)ws_size;
  const float* x_p = (const float*)d_in[0];
  const float* x_a = (const float*)d_in[1];
  const int* ei_pp = (const int*)d_in[2];
  const int* ei_aa = (const int*)d_in[3];
  const int* ei_pa = (const int*)d_in[4];
  const int* ei_ap = (const int*)d_in[5];
  const int* idxPtr = (const int*)d_in[8];
  const float* Wself_p0 = (const float*)d_in[9];
  const float* Wself_p1 = (const float*)d_in[10];
  const float* Wself_a0 = (const float*)d_in[11];
  const float* Wself_a1 = (const float*)d_in[12];
  const float* Wpp0 = (const float*)d_in[13]; const float* Wpp1 = (const float*)d_in[14];
  const float* Waa0 = (const float*)d_in[15]; const float* Waa1 = (const float*)d_in[16];
  const float* Wpa0 = (const float*)d_in[17]; /* Wpa1 unused: author L1 dropped */
  const float* Wap0 = (const float*)d_in[19]; const float* Wap1 = (const float*)d_in[20];
  const float* Wep1_pp = (const float*)d_in[21]; const float* bep1_pp = (const float*)d_in[22];
  const float* Wep2_pp = (const float*)d_in[23]; const float* bep2_pp = (const float*)d_in[24];
  const float* Wep1_aa = (const float*)d_in[25]; const float* bep1_aa = (const float*)d_in[26];
  const float* Wep2_aa = (const float*)d_in[27]; const float* bep2_aa = (const float*)d_in[28];
  const float* Wc = (const float*)d_in[29]; const float* bc = (const float*)d_in[30];

  float* out = (float*)d_out;
  float* w_pp_out = out + 5;
  float* w_aa_out = out + 5 + EPPc;

  const int* src_pp = ei_pp;  const int* dst_pp = ei_pp + EPPc;
  const int* src_aa = ei_aa;  const int* dst_aa = ei_aa + EAAc;
  const int* src_pa = ei_pa;  const int* dst_pa = ei_pa + 131072;
  const int* src_ap = ei_ap;  const int* dst_ap = ei_ap + 131072;

  // ---- workspace layout (bump allocator; cnt first: it gets memset) ----
  char* p = (char*)d_ws;
  auto alloc = [&](size_t bytes) -> void* {
    void* r = (void*)p;
    p += (bytes + 255) & ~(size_t)255;
    return r;
  };
  int* cnt     = (int*)alloc(18432 * sizeof(int));
  int* rowptr  = (int*)alloc(18438 * sizeof(int));
  int* cursor  = (int*)alloc(18432 * sizeof(int));
  int* entries = (int*)alloc(655360 * sizeof(int));
  float* Mpp  = (float*)alloc((size_t)NPn * Hh * sizeof(float));
  float* Maa  = (float*)alloc((size_t)NAn * Hh * sizeof(float));
  float* Mpa  = (float*)alloc((size_t)NAn * Hh * sizeof(float));
  float* Map  = (float*)alloc((size_t)NPn * Hh * sizeof(float));
  float* h1p0 = (float*)alloc((size_t)NPn * Hh * sizeof(float));
  float* h1a0 = (float*)alloc((size_t)NAn * Hh * sizeof(float));
  float* h1p1 = (float*)alloc((size_t)NPn * Hh * sizeof(float));
  float* h1a1 = (float*)alloc((size_t)NAn * Hh * sizeof(float));
  float* h2p0 = (float*)alloc((size_t)NPn * Hh * sizeof(float));
  float* h2a0 = (float*)alloc((size_t)NAn * Hh * sizeof(float));
  float* P1pp = (float*)alloc((size_t)NPn * 256 * sizeof(float));
  float* P2pp = (float*)alloc((size_t)NPn * 256 * sizeof(float));
  float* P1aa = (float*)alloc((size_t)NAn * 256 * sizeof(float));
  float* P2aa = (float*)alloc((size_t)NAn * 256 * sizeof(float));

  const int RP_PPD = 0, RP_AAD = 4097, RP_PAD = 6146, RP_APD = 8195;
  const int EN_PPD = 0, EN_AAD = 131072, EN_PAD = 196608, EN_APD = 327680;

  hipMemsetAsync(cnt, 0, 18432 * sizeof(int), stream);
  hist_kernel<<<2560, 256, 0, stream>>>(dst_pp, dst_aa, dst_pa, dst_ap, src_pp, src_aa, cnt);
  scan_kernel<<<6, 256, 0, stream>>>(cnt, rowptr, cursor);
  scatter_kernel<<<2560, 256, 0, stream>>>(src_pp, dst_pp, src_aa, dst_aa,
                                           src_pa, dst_pa, src_ap, dst_ap,
                                           cursor, entries);

  // ---- GNN1 (single=True: pp, aa only) ----
  {
    AggArgs a{};
    a.s[0] = {x_p, nullptr, Mpp, RP_PPD, EN_PPD, 18};
    a.s[1] = {x_a, nullptr, Maa, RP_AAD, EN_AAD, 16};
    a.start[0] = 0; a.start[1] = NPn; a.start[2] = NPn + NAn; a.nseg = 2;
    multi_agg<<<(NPn + NAn) / 8, 256, 0, stream>>>(a, rowptr, entries);
  }
  {
    GArgs g{};
    g.d[0] = {x_p, Wself_p0, Mpp, Wpp0, nullptr, nullptr, h1p0, NPn, 128, 2, 1};
    g.d[1] = {x_a, Wself_a0, Maa, Waa0, nullptr, nullptr, h1a0, NAn, 128, 2, 1};
    g.bstart[0] = 0; g.bstart[1] = 128; g.bstart[2] = 192; g.nd = 2;
    gemm_b<<<192, 256, 0, stream>>>(g);
  }
  {
    AggArgs a{};
    a.s[0] = {h1p0, nullptr, Mpp, RP_PPD, EN_PPD, 18};
    a.s[1] = {h1a0, nullptr, Maa, RP_AAD, EN_AAD, 16};
    a.start[0] = 0; a.start[1] = NPn; a.start[2] = NPn + NAn; a.nseg = 2;
    multi_agg<<<(NPn + NAn) / 8, 256, 0, stream>>>(a, rowptr, entries);
  }
  {
    GArgs g{};
    g.d[0] = {h1p0, Wself_p1, Mpp, Wpp1, nullptr, nullptr, h1p1, NPn, 128, 2, 1};
    g.d[1] = {h1a0, Wself_a1, Maa, Waa1, nullptr, nullptr, h1a1, NAn, 128, 2, 1};
    g.bstart[0] = 0; g.bstart[1] = 128; g.bstart[2] = 192; g.nd = 2;
    gemm_b<<<192, 256, 0, stream>>>(g);
  }

  // ---- edge MLP node projections: concat(h_s,h_d)@Wep1 == P1[s] + P2[d] ----
  {
    GArgs g{};
    g.d[0] = {h1p1, Wep1_pp,             nullptr, nullptr, nullptr, nullptr, P1pp, NPn, 256, 1, 0};
    g.d[1] = {h1p1, Wep1_pp + 128 * 256, nullptr, nullptr, nullptr, nullptr, P2pp, NPn, 256, 1, 0};
    g.d[2] = {h1a1, Wep1_aa,             nullptr, nullptr, nullptr, nullptr, P1aa, NAn, 256, 1, 0};
    g.d[3] = {h1a1, Wep1_aa + 128 * 256, nullptr, nullptr, nullptr, nullptr, P2aa, NAn, 256, 1, 0};
    g.bstart[0] = 0; g.bstart[1] = 256; g.bstart[2] = 512; g.bstart[3] = 640;
    g.bstart[4] = 768; g.nd = 4;
    gemm_b<<<768, 256, 0, stream>>>(g);
  }

  // ---- JAX keys: key(42) -> split -> (kpp, kaa) (partitionable fold-in) ----
  uint32_t kpp0, kpp1, kaa0, kaa1;
  { uint32_t a0 = 0, a1 = 0; tf2x32(0u, 42u, a0, a1); kpp0 = a0; kpp1 = a1; }
  { uint32_t a0 = 0, a1 = 1; tf2x32(0u, 42u, a0, a1); kaa0 = a0; kaa1 = a1; }

  // ---- fused edge-pred + sparse coalesce + gumbel top-5 + w write ----
  row_topk<<<NPn + NAn, 256, 0, stream>>>(P1pp, P2pp, bep1_pp, Wep2_pp, bep2_pp,
                                          P1aa, P2aa, bep1_aa, Wep2_aa, bep2_aa,
                                          rowptr, entries, w_pp_out, w_aa_out,
                                          kpp0, kpp1, kaa0, kaa1);

  // ---- GNN2 layer 0 (all relations; pp/aa with hard attention weights, w==0 skipped) ----
  {
    AggArgs a{};
    a.s[0] = {x_p, w_pp_out, Mpp, RP_PPD, EN_PPD, 18};
    a.s[1] = {x_a, nullptr,  Map, RP_APD, EN_APD, 0};
    a.s[2] = {x_a, w_aa_out, Maa, RP_AAD, EN_AAD, 16};
    a.s[3] = {x_p, nullptr,  Mpa, RP_PAD, EN_PAD, 0};
    a.start[0] = 0; a.start[1] = NPn; a.start[2] = 2 * NPn;
    a.start[3] = 2 * NPn + NAn; a.start[4] = 2 * NPn + 2 * NAn; a.nseg = 4;
    multi_agg<<<(2 * NPn + 2 * NAn) / 8, 256, 0, stream>>>(a, rowptr, entries);
  }
  {
    GArgs g{};
    g.d[0] = {x_p, Wself_p0, Mpp, Wpp0, Map, Wap0, h2p0, NPn, 128, 3, 1};
    g.d[1] = {x_a, Wself_a0, Maa, Waa0, Mpa, Wpa0, h2a0, NAn, 128, 3, 1};
    g.bstart[0] = 0; g.bstart[1] = 128; g.bstart[2] = 192; g.nd = 2;
    gemm_b<<<192, 256, 0, stream>>>(g);
  }

  // ---- GNN2 layer 1 only needed at one paper row -> fused with classifier ----
  final_kernel<<<1, 128, 0, stream>>>(h2p0, h2a0, idxPtr, w_pp_out,
                                      rowptr + RP_PPD, entries + EN_PPD,
                                      rowptr + RP_APD, entries + EN_APD,
                                      Wself_p1, Wpp1, Wap1, Wc, bc, out);
}

// Round 7
// 361.032 us; speedup vs baseline: 4.9665x; 1.1041x over previous
//
#include <hip/hip_runtime.h>
#include <stdint.h>

// ---------------------------------------------------------------------------
// MultiGraph hetero-GNN + gumbel-top-k edge pruning, fp32 throughout.
// Round 7: bucket CSR (fixed 128-slot buckets, single scatter kernel; hist+scan
// deleted; deg<128 guaranteed by Poisson-32 tail, relied on since r6).
// Map/Mpa (w-independent) moved into agg1; agg3 is weighted-only (tiny).
// Atomic-cursor race order preserved -> downstream fp sums bit-identical.
// PRNG: JAX threefry2x32, partitionable path (verified absmax=0.0 r1-r6).
// ---------------------------------------------------------------------------

namespace {

constexpr int NPn = 4096;
constexpr int NAn = 2048;
constexpr int Hh  = 128;
constexpr int EPPc = 131072;
constexpr int EAAc = 65536;
constexpr int KSEL = 5;
constexpr int BSLOT = 128;   // bucket capacity per node (deg<128: Poisson-32, e^-85 tail)

// bucket segments (cnt index = co + node; entries base = (co+node)*128):
// 0: pp-dst (4096)   4096: aa-dst (2048)   6144: pa-dst (2048)
// 8192: ap-dst (4096) 12288: pp-src (4096) 16384: aa-src (2048)
// payloads: pp: (other<<18)|e  aa: (other<<16)|e  pa/ap: src only

__host__ __device__ static inline void tf2x32(uint32_t k0, uint32_t k1,
                                              uint32_t& x0, uint32_t& x1) {
  uint32_t ks2 = k0 ^ k1 ^ 0x1BD11BDAu;
  x0 += k0; x1 += k1;
#define TF_R(r) { x0 += x1; x1 = (x1 << (r)) | (x1 >> (32 - (r))); x1 ^= x0; }
  TF_R(13) TF_R(15) TF_R(26) TF_R(6)
  x0 += k1;  x1 += ks2 + 1u;
  TF_R(17) TF_R(29) TF_R(16) TF_R(24)
  x0 += ks2; x1 += k0 + 2u;
  TF_R(13) TF_R(15) TF_R(26) TF_R(6)
  x0 += k0;  x1 += k1 + 3u;
  TF_R(17) TF_R(29) TF_R(16) TF_R(24)
  x0 += k1;  x1 += ks2 + 4u;
  TF_R(13) TF_R(15) TF_R(26) TF_R(6)
  x0 += ks2; x1 += k0 + 5u;
#undef TF_R
}

// ---------------- bucket scatter (replaces hist+scan+scatter) ----------------
__global__ __launch_bounds__(256) void scatter_kernel(
    const int* src_pp, const int* dst_pp, const int* src_aa, const int* dst_aa,
    const int* src_pa, const int* dst_pa, const int* src_ap, const int* dst_ap,
    int* cnt, int* entries)
{
  int i = blockIdx.x * 256 + threadIdx.x;
  int key, pl;
  if (i < 131072) {                       // pp by dst
    int e = i;
    key = 0 + dst_pp[e]; pl = (src_pp[e] << 18) | e;
  } else if (i < 196608) {                // aa by dst
    int e = i - 131072;
    key = 4096 + dst_aa[e]; pl = (src_aa[e] << 16) | e;
  } else if (i < 327680) {                // pa by dst (payload = src paper)
    int e = i - 196608;
    key = 6144 + dst_pa[e]; pl = src_pa[e];
  } else if (i < 458752) {                // ap by dst (payload = src author)
    int e = i - 327680;
    key = 8192 + dst_ap[e]; pl = src_ap[e];
  } else if (i < 589824) {                // pp by src (payload = (dst<<18)|e)
    int e = i - 458752;
    key = 12288 + src_pp[e]; pl = (dst_pp[e] << 18) | e;
  } else if (i < 655360) {                // aa by src
    int e = i - 589824;
    key = 16384 + src_aa[e]; pl = (dst_aa[e] << 16) | e;
  } else return;
  int pos = atomicAdd(&cnt[key], 1);
  if (pos < BSLOT) entries[key * BSLOT + pos] = pl;
}

// ---------------- batched mean aggregation (bucket CSR) --------------------------------
// 2 nodes per wave: half-wave (32 lanes) per node, lane covers 4 floats (float4).
// Per-node edge loop sequential in slot order (same as r2-r6 order mechanism).
struct AggSeg { const float* h; const float* w; float* M; int cntOff; int shift; };
struct AggArgs { AggSeg s[4]; int start[5]; int nseg; };

__global__ __launch_bounds__(256) void multi_agg(AggArgs a, const int* __restrict__ cnt,
                                                 const int* __restrict__ entries)
{
  int g = blockIdx.x * 8 + (threadIdx.x >> 5);   // 8 half-waves = 8 nodes per block
  int fl = (threadIdx.x & 31) << 2;              // float4 feature offset
  if (g >= a.start[a.nseg]) return;
  int si = 0;
  while (si < a.nseg - 1 && g >= a.start[si + 1]) ++si;
  AggSeg sg = a.s[si];
  int node = g - a.start[si];
  int deg = cnt[sg.cntOff + node];
  const int* ent = entries + (size_t)(sg.cntOff + node) * BSLOT;
  int b = 0, e = deg;
  const float* h = sg.h;
  int sh = sg.shift;
  float ax = 0.f, ay = 0.f, az = 0.f, aw = 0.f;
  if (sg.w) {
    unsigned mask = (1u << sh) - 1u;
    int k = b;
    for (; k + 3 < e; k += 4) {
      unsigned p0 = (unsigned)ent[k], p1 = (unsigned)ent[k + 1];
      unsigned p2 = (unsigned)ent[k + 2], p3 = (unsigned)ent[k + 3];
      float w0 = sg.w[p0 & mask], w1 = sg.w[p1 & mask];
      float w2v = sg.w[p2 & mask], w3 = sg.w[p3 & mask];
      float4 v0, v1, v2, v3;
      if (w0 != 0.f) v0 = *(const float4*)&h[(size_t)(p0 >> sh) * Hh + fl];
      if (w1 != 0.f) v1 = *(const float4*)&h[(size_t)(p1 >> sh) * Hh + fl];
      if (w2v != 0.f) v2 = *(const float4*)&h[(size_t)(p2 >> sh) * Hh + fl];
      if (w3 != 0.f) v3 = *(const float4*)&h[(size_t)(p3 >> sh) * Hh + fl];
      if (w0 != 0.f) { ax += v0.x; ay += v0.y; az += v0.z; aw += v0.w; }
      if (w1 != 0.f) { ax += v1.x; ay += v1.y; az += v1.z; aw += v1.w; }
      if (w2v != 0.f) { ax += v2.x; ay += v2.y; az += v2.z; aw += v2.w; }
      if (w3 != 0.f) { ax += v3.x; ay += v3.y; az += v3.z; aw += v3.w; }
    }
    for (; k < e; ++k) {
      unsigned pl = (unsigned)ent[k];
      float wt = sg.w[pl & mask];
      if (wt != 0.f) {
        float4 v = *(const float4*)&h[(size_t)(pl >> sh) * Hh + fl];
        ax += v.x; ay += v.y; az += v.z; aw += v.w;
      }
    }
  } else {
    int k = b;
    for (; k + 7 < e; k += 8) {
      unsigned p0 = (unsigned)ent[k],     p1 = (unsigned)ent[k + 1];
      unsigned p2 = (unsigned)ent[k + 2], p3 = (unsigned)ent[k + 3];
      unsigned p4 = (unsigned)ent[k + 4], p5 = (unsigned)ent[k + 5];
      unsigned p6 = (unsigned)ent[k + 6], p7 = (unsigned)ent[k + 7];
      float4 v0 = *(const float4*)&h[(size_t)(p0 >> sh) * Hh + fl];
      float4 v1 = *(const float4*)&h[(size_t)(p1 >> sh) * Hh + fl];
      float4 v2 = *(const float4*)&h[(size_t)(p2 >> sh) * Hh + fl];
      float4 v3 = *(const float4*)&h[(size_t)(p3 >> sh) * Hh + fl];
      float4 v4 = *(const float4*)&h[(size_t)(p4 >> sh) * Hh + fl];
      float4 v5 = *(const float4*)&h[(size_t)(p5 >> sh) * Hh + fl];
      float4 v6 = *(const float4*)&h[(size_t)(p6 >> sh) * Hh + fl];
      float4 v7 = *(const float4*)&h[(size_t)(p7 >> sh) * Hh + fl];
      ax += v0.x; ay += v0.y; az += v0.z; aw += v0.w;
      ax += v1.x; ay += v1.y; az += v1.z; aw += v1.w;
      ax += v2.x; ay += v2.y; az += v2.z; aw += v2.w;
      ax += v3.x; ay += v3.y; az += v3.z; aw += v3.w;
      ax += v4.x; ay += v4.y; az += v4.z; aw += v4.w;
      ax += v5.x; ay += v5.y; az += v5.z; aw += v5.w;
      ax += v6.x; ay += v6.y; az += v6.z; aw += v6.w;
      ax += v7.x; ay += v7.y; az += v7.z; aw += v7.w;
    }
    for (; k < e; ++k) {
      unsigned pl = (unsigned)ent[k];
      float4 v = *(const float4*)&h[(size_t)(pl >> sh) * Hh + fl];
      ax += v.x; ay += v.y; az += v.z; aw += v.w;
    }
  }
  float cd = fmaxf((float)deg, 1.0f);
  float4 o; o.x = ax / cd; o.y = ay / cd; o.z = az / cd; o.w = aw / cd;
  *(float4*)&sg.M[(size_t)node * Hh + fl] = o;
}

// ---------------- batched multi-part fp32 GEMM (r4/r6 dbuf verbatim) --------------------
struct GDesc {
  const float* A0; const float* W0; const float* A1; const float* W1;
  const float* A2; const float* W2; float* C; int M; int N; int parts; int relu;
};
struct GArgs { GDesc d[4]; int bstart[5]; int nd; };

__global__ __launch_bounds__(256) void gemm_b(GArgs g)
{
  __shared__ __align__(16) float As[2][32][68];  // [buf][k][m]
  __shared__ __align__(16) float Ws[2][32][68];  // [buf][k][n]
  int blk = blockIdx.x;
  int di = 0;
  while (di < g.nd - 1 && blk >= g.bstart[di + 1]) ++di;
  GDesc D = g.d[di];
  int local = blk - g.bstart[di];
  int nTiles = D.N >> 6;
  int bx = local % nTiles;
  int by = local / nTiles;
  int m0 = by << 6, n0 = bx << 6;
  int N = D.N;
  int tid = threadIdx.x;
  int tr = tid >> 4, tc = tid & 15;
  int r = tid >> 3, f = tid & 7;
  float acc[4][4] = {{0.f}};
  const float* Ap[3] = {D.A0, D.A1, D.A2};
  const float* Wp[3] = {D.W0, D.W1, D.W2};
  int T = D.parts << 2;            // chunks: part-major, k0 = (t&3)*32

  float4 va0, va1, vw0, vw1;
  auto ldchunk = [&](int t) {
    const float* A = Ap[t >> 2]; const float* W = Wp[t >> 2];
    int k0 = (t & 3) << 5;
    va0 = *(const float4*)&A[(size_t)(m0 + r) * 128 + k0 + f * 4];
    va1 = *(const float4*)&A[(size_t)(m0 + r + 32) * 128 + k0 + f * 4];
    vw0 = *(const float4*)&W[(size_t)(k0 + r) * N + n0 + f * 4];
    vw1 = *(const float4*)&W[(size_t)(k0 + r) * N + n0 + f * 4 + 32];
  };
  auto stchunk = [&](int buf) {
    As[buf][f * 4 + 0][r] = va0.x; As[buf][f * 4 + 1][r] = va0.y;
    As[buf][f * 4 + 2][r] = va0.z; As[buf][f * 4 + 3][r] = va0.w;
    As[buf][f * 4 + 0][r + 32] = va1.x; As[buf][f * 4 + 1][r + 32] = va1.y;
    As[buf][f * 4 + 2][r + 32] = va1.z; As[buf][f * 4 + 3][r + 32] = va1.w;
    *(float4*)&Ws[buf][r][f * 4] = vw0;
    *(float4*)&Ws[buf][r][f * 4 + 32] = vw1;
  };

  ldchunk(0);
  stchunk(0);
  __syncthreads();
  for (int t = 0; t < T; ++t) {
    int cur = t & 1;
    bool more = (t + 1 < T);
    if (more) ldchunk(t + 1);      // global loads in flight during compute
#pragma unroll
    for (int k = 0; k < 32; ++k) {
      float4 a = *(const float4*)&As[cur][k][tr * 4];
      float4 b = *(const float4*)&Ws[cur][k][tc * 4];
      acc[0][0] += a.x * b.x; acc[0][1] += a.x * b.y; acc[0][2] += a.x * b.z; acc[0][3] += a.x * b.w;
      acc[1][0] += a.y * b.x; acc[1][1] += a.y * b.y; acc[1][2] += a.y * b.z; acc[1][3] += a.y * b.w;
      acc[2][0] += a.z * b.x; acc[2][1] += a.z * b.y; acc[2][2] += a.z * b.z; acc[2][3] += a.z * b.w;
      acc[3][0] += a.w * b.x; acc[3][1] += a.w * b.y; acc[3][2] += a.w * b.z; acc[3][3] += a.w * b.w;
    }
    if (more) stchunk(cur ^ 1);
    __syncthreads();
  }
#pragma unroll
  for (int i = 0; i < 4; ++i) {
    float4 v;
    v.x = acc[i][0]; v.y = acc[i][1]; v.z = acc[i][2]; v.w = acc[i][3];
    if (D.relu) {
      v.x = fmaxf(v.x, 0.f); v.y = fmaxf(v.y, 0.f);
      v.z = fmaxf(v.z, 0.f); v.w = fmaxf(v.w, 0.f);
    }
    *(float4*)&D.C[(size_t)(m0 + tr * 4 + i) * N + n0 + tc * 4] = v;
  }
}

// ---------------- fused edge-MLP + sparse coalesce + masked gumbel top-5 + w write ------
// r6 verbatim except bucket addressing (beg = (co+row)*128, deg = cnt[co+row]).
__global__ __launch_bounds__(256) void row_topk(
    const float* __restrict__ P1pp, const float* __restrict__ P2pp,
    const float* __restrict__ b1pp, const float* __restrict__ W2pp,
    const float* __restrict__ b2pp,
    const float* __restrict__ P1aa, const float* __restrict__ P2aa,
    const float* __restrict__ b1aa, const float* __restrict__ W2aa,
    const float* __restrict__ b2aa,
    const int* __restrict__ cnt, const int* __restrict__ entries,
    float* __restrict__ w_pp, float* __restrict__ w_aa,
    uint32_t kpp0, uint32_t kpp1, uint32_t kaa0, uint32_t kaa1)
{
  __shared__ float P1s[256], b1s[256], w2s[256];
  __shared__ int   dS[128];
  __shared__ float pS[128];
  __shared__ int   sel5[KSEL];
  int blk = blockIdx.x, tid = threadIdx.x;
  int lane = tid & 63, wv = tid >> 6;
  int row, Ncols, shift, co; unsigned mask;
  const float* P1; const float* P2; const float* b1; const float* W2; const float* b2;
  float* wout; uint32_t k0, k1;
  if (blk < NPn) {
    row = blk; Ncols = NPn; shift = 18; mask = 0x3FFFFu; co = 12288;
    P1 = P1pp; P2 = P2pp; b1 = b1pp; W2 = W2pp; b2 = b2pp;
    wout = w_pp; k0 = kpp0; k1 = kpp1;
  } else {
    row = blk - NPn; Ncols = NAn; shift = 16; mask = 0xFFFFu; co = 16384;
    P1 = P1aa; P2 = P2aa; b1 = b1aa; W2 = W2aa; b2 = b2aa;
    wout = w_aa; k0 = kaa0; k1 = kaa1;
  }
  const int* ent = entries + (size_t)(co + row) * BSLOT;
  int deg = cnt[co + row];
  P1s[tid] = P1[(size_t)row * 256 + tid];
  b1s[tid] = b1[tid];
  w2s[tid] = W2[tid * 2];
  __syncthreads();
  float bias2 = b2[0];
  // --- edge phase: 4 edges per wave, r4-identical arithmetic; lane0 -> LDS slots ---
  int j = lane << 2;
  for (int k = wv * 4; k < deg; k += 16) {
    int n = deg - k; if (n > 4) n = 4;
    unsigned pl0 = (unsigned)ent[k];
    unsigned pl1 = (n > 1) ? (unsigned)ent[k + 1] : pl0;
    unsigned pl2 = (n > 2) ? (unsigned)ent[k + 2] : pl0;
    unsigned pl3 = (n > 3) ? (unsigned)ent[k + 3] : pl0;
    int d0 = (int)(pl0 >> shift), d1 = (int)(pl1 >> shift);
    int d2 = (int)(pl2 >> shift), d3 = (int)(pl3 >> shift);
    float4 q0 = *(const float4*)&P2[(size_t)d0 * 256 + j];
    float4 q1 = *(const float4*)&P2[(size_t)d1 * 256 + j];
    float4 q2 = *(const float4*)&P2[(size_t)d2 * 256 + j];
    float4 q3 = *(const float4*)&P2[(size_t)d3 * 256 + j];
    float pa = P1s[j + 0], pb = P1s[j + 1], pc = P1s[j + 2], pd = P1s[j + 3];
    float ba = b1s[j + 0], bb = b1s[j + 1], bc_ = b1s[j + 2], bd = b1s[j + 3];
    float wa = w2s[j + 0], wb = w2s[j + 1], wc = w2s[j + 2], wd = w2s[j + 3];
    float s0 = fmaxf(pa + q0.x + ba, 0.f) * wa + fmaxf(pb + q0.y + bb, 0.f) * wb +
               fmaxf(pc + q0.z + bc_, 0.f) * wc + fmaxf(pd + q0.w + bd, 0.f) * wd;
    float s1 = fmaxf(pa + q1.x + ba, 0.f) * wa + fmaxf(pb + q1.y + bb, 0.f) * wb +
               fmaxf(pc + q1.z + bc_, 0.f) * wc + fmaxf(pd + q1.w + bd, 0.f) * wd;
    float s2 = fmaxf(pa + q2.x + ba, 0.f) * wa + fmaxf(pb + q2.y + bb, 0.f) * wb +
               fmaxf(pc + q2.z + bc_, 0.f) * wc + fmaxf(pd + q2.w + bd, 0.f) * wd;
    float s3 = fmaxf(pa + q3.x + ba, 0.f) * wa + fmaxf(pb + q3.y + bb, 0.f) * wb +
               fmaxf(pc + q3.z + bc_, 0.f) * wc + fmaxf(pd + q3.w + bd, 0.f) * wd;
    for (int off = 32; off; off >>= 1) {
      s0 += __shfl_down(s0, off);
      s1 += __shfl_down(s1, off);
      s2 += __shfl_down(s2, off);
      s3 += __shfl_down(s3, off);
    }
    if (lane == 0) {
      dS[k] = d0; pS[k] = s0 + bias2;
      if (n > 1) { dS[k + 1] = d1; pS[k + 1] = s1 + bias2; }
      if (n > 2) { dS[k + 2] = d2; pS[k + 2] = s2 + bias2; }
      if (n > 3) { dS[k + 3] = d3; pS[k + 3] = s3 + bias2; }
    }
  }
  __syncthreads();
  if (deg > 0 && wv == 0) {
    // --- dedupe (ascending-slot sums) + gumbel + top-5, all in wave 0 ---
    int   e0 = (lane < deg) ? dS[lane] : -1;
    float q0v = (lane < deg) ? pS[lane] : 0.f;
    bool  two = (deg > 64);
    int   e1 = -1; float q1v = 0.f;
    if (two && 64 + lane < deg) { e1 = dS[64 + lane]; q1v = pS[64 + lane]; }
    float a0 = 0.f, a1 = 0.f;
    bool lead0 = (e0 >= 0), lead1 = (e1 >= 0);
    for (int j2 = 0; j2 < deg; ++j2) {
      int bj; float bp;
      if (j2 < 64) { bj = __shfl(e0, j2); bp = __shfl(q0v, j2); }
      else         { bj = __shfl(e1, j2 - 64); bp = __shfl(q1v, j2 - 64); }
      if (e0 >= 0 && bj == e0) { a0 += bp; if (j2 < lane) lead0 = false; }
      if (e1 >= 0 && bj == e1) { a1 += bp; if (j2 < 64 + lane) lead1 = false; }
    }
    uint32_t rowbase = (uint32_t)row * (uint32_t)Ncols;
    float y0 = -1e9f, y1 = -1e9f;
    bool c0 = lead0 && (a0 > 0.f);
    if (c0) {
      uint32_t x0 = 0u, x1 = rowbase + (uint32_t)e0;
      tf2x32(k0, k1, x0, x1);
      uint32_t bits = x0 ^ x1;
      float fv = __uint_as_float((bits >> 9) | 0x3f800000u) - 1.0f;
      float u = fmaxf(1e-10f, fv + 1e-10f);
      y0 = a0 + (-logf(-logf(u)));
    }
    bool c1 = lead1 && (a1 > 0.f);
    if (c1) {
      uint32_t x0 = 0u, x1 = rowbase + (uint32_t)e1;
      tf2x32(k0, k1, x0, x1);
      uint32_t bits = x0 ^ x1;
      float fv = __uint_as_float((bits >> 9) | 0x3f800000u) - 1.0f;
      float u = fmaxf(1e-10f, fv + 1e-10f);
      y1 = a1 + (-logf(-logf(u)));
    }
    int cnt2 = __popcll(__ballot(c0)) + __popcll(__ballot(c1));
    int nsel = cnt2 < KSEL ? cnt2 : KSEL;
    for (int it = 0; it < nsel; ++it) {
      float best; int bc;
      if (y1 > y0 || (y1 == y0 && (unsigned)e1 < (unsigned)e0)) { best = y1; bc = e1; }
      else { best = y0; bc = e0; }
      for (int m = 32; m; m >>= 1) {
        float ov = __shfl_xor(best, m); int oc = __shfl_xor(bc, m);
        if (ov > best || (ov == best && (unsigned)oc < (unsigned)bc)) { best = ov; bc = oc; }
      }
      if (lane == 0) sel5[it] = bc;
      if (e0 == bc) y0 = -3.0e38f;
      if (e1 == bc) y1 = -3.0e38f;
    }
    if (nsel < KSEL && lane == 0) {
      // fill remaining with smallest column indices not yet selected
      int c = 0;
      for (int it = nsel; it < KSEL; ++it) {
        for (;;) {
          bool used = false;
          for (int q = 0; q < it; ++q) used |= (sel5[q] == c);
          if (!used) break;
          ++c;
        }
        sel5[it] = c++;
      }
    }
  }
  __syncthreads();
  // --- write hard 0/1 weights onto this row's edges ---
  for (int k = tid; k < deg; k += 256) {
    unsigned pl = (unsigned)ent[k];
    int d = (int)(pl >> shift);
    int e = (int)(pl & mask);
    float v = 0.f;
#pragma unroll
    for (int q = 0; q < KSEL; ++q) v = (sel5[q] == d) ? 1.f : v;
    wout[e] = v;
  }
}

// ---------------- fused GNN2-layer1 (single row) + classifier (bucket CSR) --------------
__global__ __launch_bounds__(128) void final_kernel(
    const float* __restrict__ hp, const float* __restrict__ ha,
    const int* __restrict__ idxPtr, const float* __restrict__ wpp,
    const int* __restrict__ cnt, const int* __restrict__ entries,
    const float* __restrict__ Wself, const float* __restrict__ Wpp,
    const float* __restrict__ Wap,
    const float* __restrict__ Wc, const float* __restrict__ bc,
    float* __restrict__ out)
{
  __shared__ float selfr[128], mpp[128], mapr[128], t[128];
  int tid = threadIdx.x;
  int idx = idxPtr[0];
  selfr[tid] = hp[(size_t)idx * 128 + tid];
  {
    int deg = cnt[idx];                                   // pp-dst bucket
    const int* ent = entries + (size_t)idx * BSLOT;
    float acc = 0.f;
    for (int k = 0; k < deg; ++k) {
      unsigned pl = (unsigned)ent[k];
      int s = (int)(pl >> 18);
      int e = (int)(pl & 0x3FFFFu);
      acc += wpp[e] * hp[(size_t)s * 128 + tid];
    }
    mpp[tid] = acc / fmaxf((float)deg, 1.0f);
  }
  {
    int deg = cnt[8192 + idx];                            // ap-dst bucket
    const int* ent = entries + (size_t)(8192 + idx) * BSLOT;
    float acc = 0.f;
    for (int k = 0; k < deg; ++k) {
      int s = ent[k];
      acc += ha[(size_t)s * 128 + tid];
    }
    mapr[tid] = acc / fmaxf((float)deg, 1.0f);
  }
  __syncthreads();
  float s = 0.f;
  for (int m = 0; m < 128; ++m) {
    s += selfr[m] * Wself[m * 128 + tid] + mpp[m] * Wpp[m * 128 + tid] +
         mapr[m] * Wap[m * 128 + tid];
  }
  t[tid] = fmaxf(s, 0.f);
  __syncthreads();
  if (tid < 5) {
    float y = bc[tid];
    for (int k = 0; k < 128; ++k) y += t[k] * Wc[k * 5 + tid];
    out[tid] = y;
  }
}

}  // namespace

extern "C" void kernel_launch(void* const* d_in, const int* in_sizes, int n_in,
                              void* d_out, int out_size, void* d_ws, size_t ws_size,
                              hipStream_t stream)
{
  (void)in_sizes; (void)n_in; (void)out_size; (void)ws_size;
  const float* x_p = (const float*)d_in[0];
  const float* x_a = (const float*)d_in[1];
  const int* ei_pp = (const int*)d_in[2];
  const int* ei_aa = (const int*)d_in[3];
  const int* ei_pa = (const int*)d_in[4];
  const int* ei_ap = (const int*)d_in[5];
  const int* idxPtr = (const int*)d_in[8];
  const float* Wself_p0 = (const float*)d_in[9];
  const float* Wself_p1 = (const float*)d_in[10];
  const float* Wself_a0 = (const float*)d_in[11];
  const float* Wself_a1 = (const float*)d_in[12];
  const float* Wpp0 = (const float*)d_in[13]; const float* Wpp1 = (const float*)d_in[14];
  const float* Waa0 = (const float*)d_in[15]; const float* Waa1 = (const float*)d_in[16];
  const float* Wpa0 = (const float*)d_in[17]; /* Wpa1 unused: author L1 dropped */
  const float* Wap0 = (const float*)d_in[19]; const float* Wap1 = (const float*)d_in[20];
  const float* Wep1_pp = (const float*)d_in[21]; const float* bep1_pp = (const float*)d_in[22];
  const float* Wep2_pp = (const float*)d_in[23]; const float* bep2_pp = (const float*)d_in[24];
  const float* Wep1_aa = (const float*)d_in[25]; const float* bep1_aa = (const float*)d_in[26];
  const float* Wep2_aa = (const float*)d_in[27]; const float* bep2_aa = (const float*)d_in[28];
  const float* Wc = (const float*)d_in[29]; const float* bc = (const float*)d_in[30];

  float* out = (float*)d_out;
  float* w_pp_out = out + 5;
  float* w_aa_out = out + 5 + EPPc;

  const int* src_pp = ei_pp;  const int* dst_pp = ei_pp + EPPc;
  const int* src_aa = ei_aa;  const int* dst_aa = ei_aa + EAAc;
  const int* src_pa = ei_pa;  const int* dst_pa = ei_pa + 131072;
  const int* src_ap = ei_ap;  const int* dst_ap = ei_ap + 131072;

  // ---- workspace layout (bump allocator; cnt first: it gets memset) ----
  char* p = (char*)d_ws;
  auto alloc = [&](size_t bytes) -> void* {
    void* r = (void*)p;
    p += (bytes + 255) & ~(size_t)255;
    return r;
  };
  int* cnt     = (int*)alloc(18432 * sizeof(int));
  int* entries = (int*)alloc((size_t)18432 * BSLOT * sizeof(int));  // 9.4 MB buckets
  float* Mpp  = (float*)alloc((size_t)NPn * Hh * sizeof(float));
  float* Maa  = (float*)alloc((size_t)NAn * Hh * sizeof(float));
  float* Mpa  = (float*)alloc((size_t)NAn * Hh * sizeof(float));
  float* Map  = (float*)alloc((size_t)NPn * Hh * sizeof(float));
  float* h1p0 = (float*)alloc((size_t)NPn * Hh * sizeof(float));
  float* h1a0 = (float*)alloc((size_t)NAn * Hh * sizeof(float));
  float* h1p1 = (float*)alloc((size_t)NPn * Hh * sizeof(float));
  float* h1a1 = (float*)alloc((size_t)NAn * Hh * sizeof(float));
  float* h2p0 = (float*)alloc((size_t)NPn * Hh * sizeof(float));
  float* h2a0 = (float*)alloc((size_t)NAn * Hh * sizeof(float));
  float* P1pp = (float*)alloc((size_t)NPn * 256 * sizeof(float));
  float* P2pp = (float*)alloc((size_t)NPn * 256 * sizeof(float));
  float* P1aa = (float*)alloc((size_t)NAn * 256 * sizeof(float));
  float* P2aa = (float*)alloc((size_t)NAn * 256 * sizeof(float));

  // bucket cnt offsets
  const int CO_PPD = 0, CO_AAD = 4096, CO_PAD = 6144, CO_APD = 8192;

  hipMemsetAsync(cnt, 0, 18432 * sizeof(int), stream);
  scatter_kernel<<<2560, 256, 0, stream>>>(src_pp, dst_pp, src_aa, dst_aa,
                                           src_pa, dst_pa, src_ap, dst_ap,
                                           cnt, entries);

  // ---- agg1: GNN1-L0 means (pp,aa) + w-independent GNN2 means (ap,pa) ----
  {
    AggArgs a{};
    a.s[0] = {x_p, nullptr, Mpp, CO_PPD, 18};
    a.s[1] = {x_a, nullptr, Maa, CO_AAD, 16};
    a.s[2] = {x_a, nullptr, Map, CO_APD, 0};
    a.s[3] = {x_p, nullptr, Mpa, CO_PAD, 0};
    a.start[0] = 0; a.start[1] = NPn; a.start[2] = NPn + NAn;
    a.start[3] = 2 * NPn + NAn; a.start[4] = 2 * NPn + 2 * NAn; a.nseg = 4;
    multi_agg<<<(2 * NPn + 2 * NAn) / 8, 256, 0, stream>>>(a, cnt, entries);
  }
  {
    GArgs g{};
    g.d[0] = {x_p, Wself_p0, Mpp, Wpp0, nullptr, nullptr, h1p0, NPn, 128, 2, 1};
    g.d[1] = {x_a, Wself_a0, Maa, Waa0, nullptr, nullptr, h1a0, NAn, 128, 2, 1};
    g.bstart[0] = 0; g.bstart[1] = 128; g.bstart[2] = 192; g.nd = 2;
    gemm_b<<<192, 256, 0, stream>>>(g);
  }
  {
    AggArgs a{};
    a.s[0] = {h1p0, nullptr, Mpp, CO_PPD, 18};
    a.s[1] = {h1a0, nullptr, Maa, CO_AAD, 16};
    a.start[0] = 0; a.start[1] = NPn; a.start[2] = NPn + NAn; a.nseg = 2;
    multi_agg<<<(NPn + NAn) / 8, 256, 0, stream>>>(a, cnt, entries);
  }
  {
    GArgs g{};
    g.d[0] = {h1p0, Wself_p1, Mpp, Wpp1, nullptr, nullptr, h1p1, NPn, 128, 2, 1};
    g.d[1] = {h1a0, Wself_a1, Maa, Waa1, nullptr, nullptr, h1a1, NAn, 128, 2, 1};
    g.bstart[0] = 0; g.bstart[1] = 128; g.bstart[2] = 192; g.nd = 2;
    gemm_b<<<192, 256, 0, stream>>>(g);
  }

  // ---- edge MLP node projections: concat(h_s,h_d)@Wep1 == P1[s] + P2[d] ----
  {
    GArgs g{};
    g.d[0] = {h1p1, Wep1_pp,             nullptr, nullptr, nullptr, nullptr, P1pp, NPn, 256, 1, 0};
    g.d[1] = {h1p1, Wep1_pp + 128 * 256, nullptr, nullptr, nullptr, nullptr, P2pp, NPn, 256, 1, 0};
    g.d[2] = {h1a1, Wep1_aa,             nullptr, nullptr, nullptr, nullptr, P1aa, NAn, 256, 1, 0};
    g.d[3] = {h1a1, Wep1_aa + 128 * 256, nullptr, nullptr, nullptr, nullptr, P2aa, NAn, 256, 1, 0};
    g.bstart[0] = 0; g.bstart[1] = 256; g.bstart[2] = 512; g.bstart[3] = 640;
    g.bstart[4] = 768; g.nd = 4;
    gemm_b<<<768, 256, 0, stream>>>(g);
  }

  // ---- JAX keys: key(42) -> split -> (kpp, kaa) (partitionable fold-in) ----
  uint32_t kpp0, kpp1, kaa0, kaa1;
  { uint32_t a0 = 0, a1 = 0; tf2x32(0u, 42u, a0, a1); kpp0 = a0; kpp1 = a1; }
  { uint32_t a0 = 0, a1 = 1; tf2x32(0u, 42u, a0, a1); kaa0 = a0; kaa1 = a1; }

  // ---- fused edge-pred + sparse coalesce + gumbel top-5 + w write ----
  row_topk<<<NPn + NAn, 256, 0, stream>>>(P1pp, P2pp, bep1_pp, Wep2_pp, bep2_pp,
                                          P1aa, P2aa, bep1_aa, Wep2_aa, bep2_aa,
                                          cnt, entries, w_pp_out, w_aa_out,
                                          kpp0, kpp1, kaa0, kaa1);

  // ---- agg3: weighted pp/aa means only (Map/Mpa already done in agg1) ----
  {
    AggArgs a{};
    a.s[0] = {x_p, w_pp_out, Mpp, CO_PPD, 18};
    a.s[1] = {x_a, w_aa_out, Maa, CO_AAD, 16};
    a.start[0] = 0; a.start[1] = NPn; a.start[2] = NPn + NAn; a.nseg = 2;
    multi_agg<<<(NPn + NAn) / 8, 256, 0, stream>>>(a, cnt, entries);
  }
  {
    GArgs g{};
    g.d[0] = {x_p, Wself_p0, Mpp, Wpp0, Map, Wap0, h2p0, NPn, 128, 3, 1};
    g.d[1] = {x_a, Wself_a0, Maa, Waa0, Mpa, Wpa0, h2a0, NAn, 128, 3, 1};
    g.bstart[0] = 0; g.bstart[1] = 128; g.bstart[2] = 192; g.nd = 2;
    gemm_b<<<192, 256, 0, stream>>>(g);
  }

  // ---- GNN2 layer 1 only needed at one paper row -> fused with classifier ----
  final_kernel<<<1, 128, 0, stream>>>(h2p0, h2a0, idxPtr, w_pp_out,
                                      cnt, entries,
                                      Wself_p1, Wpp1, Wap1, Wc, bc, out);
}

// Round 8
// 359.700 us; speedup vs baseline: 4.9849x; 1.0037x over previous
//
#include <hip/hip_runtime.h>
#include <stdint.h>

// ---------------------------------------------------------------------------
// MultiGraph hetero-GNN + gumbel-top-k edge pruning, fp32 throughout.
// Round 8: producer-consumer fusion agg+GEMM per block (8 nodes/block; a
// block's agg rows feed only that block's GEMM rows -> NO grid sync, unlike
// r5). Three fused_layer dispatches replace agg1/gemm1/agg2/gemm2/gemmP/
// agg3/gemm3; h1p1 never materialized (P-projections from LDS h rows).
// All per-output fp chains preserved (agg slot-ascending, GEMM part-major
// k-ascending, P k-ascending) -> bit-exact vs r7.
// PRNG: JAX threefry2x32, partitionable path (verified absmax=0.0 r1-r7).
// ---------------------------------------------------------------------------

namespace {

constexpr int NPn = 4096;
constexpr int NAn = 2048;
constexpr int Hh  = 128;
constexpr int EPPc = 131072;
constexpr int EAAc = 65536;
constexpr int KSEL = 5;
constexpr int BSLOT = 128;   // bucket capacity per node (deg<128: Poisson-32, e^-85 tail)

// bucket segments (cnt index = co + node; entries base = (co+node)*128):
// 0: pp-dst (4096)   4096: aa-dst (2048)   6144: pa-dst (2048)
// 8192: ap-dst (4096) 12288: pp-src (4096) 16384: aa-src (2048)
// payloads: pp: (other<<18)|e  aa: (other<<16)|e  pa/ap: src only

__host__ __device__ static inline void tf2x32(uint32_t k0, uint32_t k1,
                                              uint32_t& x0, uint32_t& x1) {
  uint32_t ks2 = k0 ^ k1 ^ 0x1BD11BDAu;
  x0 += k0; x1 += k1;
#define TF_R(r) { x0 += x1; x1 = (x1 << (r)) | (x1 >> (32 - (r))); x1 ^= x0; }
  TF_R(13) TF_R(15) TF_R(26) TF_R(6)
  x0 += k1;  x1 += ks2 + 1u;
  TF_R(17) TF_R(29) TF_R(16) TF_R(24)
  x0 += ks2; x1 += k0 + 2u;
  TF_R(13) TF_R(15) TF_R(26) TF_R(6)
  x0 += k0;  x1 += k1 + 3u;
  TF_R(17) TF_R(29) TF_R(16) TF_R(24)
  x0 += k1;  x1 += ks2 + 4u;
  TF_R(13) TF_R(15) TF_R(26) TF_R(6)
  x0 += ks2; x1 += k0 + 5u;
#undef TF_R
}

// ---------------- bucket scatter (r7 verbatim) ----------------
__global__ __launch_bounds__(256) void scatter_kernel(
    const int* src_pp, const int* dst_pp, const int* src_aa, const int* dst_aa,
    const int* src_pa, const int* dst_pa, const int* src_ap, const int* dst_ap,
    int* cnt, int* entries)
{
  int i = blockIdx.x * 256 + threadIdx.x;
  int key, pl;
  if (i < 131072) {                       // pp by dst
    int e = i;
    key = 0 + dst_pp[e]; pl = (src_pp[e] << 18) | e;
  } else if (i < 196608) {                // aa by dst
    int e = i - 131072;
    key = 4096 + dst_aa[e]; pl = (src_aa[e] << 16) | e;
  } else if (i < 327680) {                // pa by dst (payload = src paper)
    int e = i - 196608;
    key = 6144 + dst_pa[e]; pl = src_pa[e];
  } else if (i < 458752) {                // ap by dst (payload = src author)
    int e = i - 327680;
    key = 8192 + dst_ap[e]; pl = src_ap[e];
  } else if (i < 589824) {                // pp by src (payload = (dst<<18)|e)
    int e = i - 458752;
    key = 12288 + src_pp[e]; pl = (dst_pp[e] << 18) | e;
  } else if (i < 655360) {                // aa by src
    int e = i - 589824;
    key = 16384 + src_aa[e]; pl = (dst_aa[e] << 16) | e;
  } else return;
  int pos = atomicAdd(&cnt[key], 1);
  if (pos < BSLOT) entries[key * BSLOT + pos] = pl;
}

// ---------------- fused agg + GEMM (+ optional P projections) --------------------------
// 8 nodes per block. Agg: half-wave per node (r7 multi_agg body) -> Ms LDS (or Mout
// global for agg-only segments). GEMM: C[8][128] = sum parts (Xs=self, Ms, Zs=A2),
// per-output chain = part-major, k 0..127 ascending (identical to r7 gemm_b).
// P stage: P1/P2[8][256] from LDS h rows, k ascending (identical to r7 gemmP).
struct FDesc {
  const float* gsrc; const float* wArr; int cntOff; int shift;
  float* Mout;                                  // agg-only output (when W0 == null)
  const float* Aself; const float* W0; const float* W1;
  const float* A2;  const float* W2;            // optional part 2
  float* C; int relu;                           // C may be null (P-only)
  const float* WP; float* P1; float* P2;        // optional P stage
};
struct FArgs { FDesc d[4]; int bstart[5]; int nd; };

__global__ __launch_bounds__(256) void fused_layer(FArgs fa, const int* __restrict__ cnt,
                                                   const int* __restrict__ entries)
{
  __shared__ __align__(16) float Ms[8][128];
  __shared__ __align__(16) float Xs[8][128];
  __shared__ __align__(16) float Zs[8][128];
  __shared__ __align__(16) float Ws[32][128];
  int blk = blockIdx.x, tid = threadIdx.x;
  int di = 0;
  while (di < fa.nd - 1 && blk >= fa.bstart[di + 1]) ++di;
  FDesc D = fa.d[di];
  int node0 = (blk - fa.bstart[di]) * 8;
  // ---- agg phase (r7 multi_agg body; half-wave per node) ----
  {
    int hw = tid >> 5;
    int node = node0 + hw;
    int fl = (tid & 31) << 2;
    int deg = cnt[D.cntOff + node];
    const int* ent = entries + (size_t)(D.cntOff + node) * BSLOT;
    const float* h = D.gsrc;
    int sh = D.shift;
    float ax = 0.f, ay = 0.f, az = 0.f, aw = 0.f;
    if (D.wArr) {
      unsigned mask = (1u << sh) - 1u;
      int k = 0;
      for (; k + 3 < deg; k += 4) {
        unsigned p0 = (unsigned)ent[k], p1 = (unsigned)ent[k + 1];
        unsigned p2 = (unsigned)ent[k + 2], p3 = (unsigned)ent[k + 3];
        float w0 = D.wArr[p0 & mask], w1 = D.wArr[p1 & mask];
        float w2v = D.wArr[p2 & mask], w3 = D.wArr[p3 & mask];
        float4 v0, v1, v2, v3;
        if (w0 != 0.f) v0 = *(const float4*)&h[(size_t)(p0 >> sh) * Hh + fl];
        if (w1 != 0.f) v1 = *(const float4*)&h[(size_t)(p1 >> sh) * Hh + fl];
        if (w2v != 0.f) v2 = *(const float4*)&h[(size_t)(p2 >> sh) * Hh + fl];
        if (w3 != 0.f) v3 = *(const float4*)&h[(size_t)(p3 >> sh) * Hh + fl];
        if (w0 != 0.f) { ax += v0.x; ay += v0.y; az += v0.z; aw += v0.w; }
        if (w1 != 0.f) { ax += v1.x; ay += v1.y; az += v1.z; aw += v1.w; }
        if (w2v != 0.f) { ax += v2.x; ay += v2.y; az += v2.z; aw += v2.w; }
        if (w3 != 0.f) { ax += v3.x; ay += v3.y; az += v3.z; aw += v3.w; }
      }
      for (; k < deg; ++k) {
        unsigned pl = (unsigned)ent[k];
        float wt = D.wArr[pl & mask];
        if (wt != 0.f) {
          float4 v = *(const float4*)&h[(size_t)(pl >> sh) * Hh + fl];
          ax += v.x; ay += v.y; az += v.z; aw += v.w;
        }
      }
    } else {
      int k = 0;
      for (; k + 7 < deg; k += 8) {
        unsigned p0 = (unsigned)ent[k],     p1 = (unsigned)ent[k + 1];
        unsigned p2 = (unsigned)ent[k + 2], p3 = (unsigned)ent[k + 3];
        unsigned p4 = (unsigned)ent[k + 4], p5 = (unsigned)ent[k + 5];
        unsigned p6 = (unsigned)ent[k + 6], p7 = (unsigned)ent[k + 7];
        float4 v0 = *(const float4*)&h[(size_t)(p0 >> sh) * Hh + fl];
        float4 v1 = *(const float4*)&h[(size_t)(p1 >> sh) * Hh + fl];
        float4 v2 = *(const float4*)&h[(size_t)(p2 >> sh) * Hh + fl];
        float4 v3 = *(const float4*)&h[(size_t)(p3 >> sh) * Hh + fl];
        float4 v4 = *(const float4*)&h[(size_t)(p4 >> sh) * Hh + fl];
        float4 v5 = *(const float4*)&h[(size_t)(p5 >> sh) * Hh + fl];
        float4 v6 = *(const float4*)&h[(size_t)(p6 >> sh) * Hh + fl];
        float4 v7 = *(const float4*)&h[(size_t)(p7 >> sh) * Hh + fl];
        ax += v0.x; ay += v0.y; az += v0.z; aw += v0.w;
        ax += v1.x; ay += v1.y; az += v1.z; aw += v1.w;
        ax += v2.x; ay += v2.y; az += v2.z; aw += v2.w;
        ax += v3.x; ay += v3.y; az += v3.z; aw += v3.w;
        ax += v4.x; ay += v4.y; az += v4.z; aw += v4.w;
        ax += v5.x; ay += v5.y; az += v5.z; aw += v5.w;
        ax += v6.x; ay += v6.y; az += v6.z; aw += v6.w;
        ax += v7.x; ay += v7.y; az += v7.z; aw += v7.w;
      }
      for (; k < deg; ++k) {
        unsigned pl = (unsigned)ent[k];
        float4 v = *(const float4*)&h[(size_t)(pl >> sh) * Hh + fl];
        ax += v.x; ay += v.y; az += v.z; aw += v.w;
      }
    }
    float cd = fmaxf((float)deg, 1.0f);
    float4 o; o.x = ax / cd; o.y = ay / cd; o.z = az / cd; o.w = aw / cd;
    if (D.W0 == nullptr) {
      *(float4*)&D.Mout[(size_t)node * Hh + fl] = o;
    } else {
      *(float4*)&Ms[hw][fl] = o;
    }
  }
  if (D.W0 == nullptr) return;   // agg-only block (uniform per block)
  // ---- stage self rows (and part-2 rows): contiguous, coalesced ----
  {
    int rm = tid >> 5, cq = (tid & 31) << 2;
    *(float4*)&Xs[rm][cq] = *(const float4*)&D.Aself[(size_t)(node0 + rm) * 128 + cq];
    if (D.A2)
      *(float4*)&Zs[rm][cq] = *(const float4*)&D.A2[(size_t)(node0 + rm) * 128 + cq];
  }
  // ---- GEMM: per thread 4 outputs C[m][nq*4..+3]; part-major, k ascending ----
  int m = tid >> 5, nq = tid & 31;
  float4 accv = {0.f, 0.f, 0.f, 0.f};
  int parts = D.A2 ? 3 : 2;
  for (int p = 0; p < parts; ++p) {
    const float* W = (p == 0) ? D.W0 : (p == 1) ? D.W1 : D.W2;
    for (int c = 0; c < 4; ++c) {
      __syncthreads();                   // prev chunk consumed / agg+stage visible
      {
        int r = tid >> 3, f = (tid & 7) << 4;
        const float* srcp = &W[(size_t)(c * 32 + r) * 128 + f];
        *(float4*)&Ws[r][f]      = *(const float4*)&srcp[0];
        *(float4*)&Ws[r][f + 4]  = *(const float4*)&srcp[4];
        *(float4*)&Ws[r][f + 8]  = *(const float4*)&srcp[8];
        *(float4*)&Ws[r][f + 12] = *(const float4*)&srcp[12];
      }
      __syncthreads();
#define KCHUNK(AR)                                              \
      _Pragma("unroll")                                         \
      for (int k = 0; k < 32; ++k) {                            \
        float a = AR[m][c * 32 + k];                            \
        float4 wv = *(const float4*)&Ws[k][nq << 2];            \
        accv.x += a * wv.x; accv.y += a * wv.y;                 \
        accv.z += a * wv.z; accv.w += a * wv.w;                 \
      }
      if (p == 0) { KCHUNK(Xs) } else if (p == 1) { KCHUNK(Ms) } else { KCHUNK(Zs) }
#undef KCHUNK
    }
  }
  if (D.relu) {
    accv.x = fmaxf(accv.x, 0.f); accv.y = fmaxf(accv.y, 0.f);
    accv.z = fmaxf(accv.z, 0.f); accv.w = fmaxf(accv.w, 0.f);
  }
  if (D.C)
    *(float4*)&D.C[(size_t)(node0 + m) * 128 + (nq << 2)] = accv;
  if (D.WP == nullptr) return;
  // ---- P stage: h rows -> LDS (reuse Xs), then P1/P2 = h @ WP halves ----
  __syncthreads();
  *(float4*)&Xs[m][nq << 2] = accv;
  __syncthreads();
  int c0 = nq << 3;                      // 8 cols per thread
  float4 p1a = {0,0,0,0}, p1b = {0,0,0,0}, p2a = {0,0,0,0}, p2b = {0,0,0,0};
  for (int k = 0; k < 128; ++k) {
    float a = Xs[m][k];
    const float* w1 = &D.WP[(size_t)k * 256 + c0];
    const float* w2 = &D.WP[(size_t)(128 + k) * 256 + c0];
    float4 u1a = *(const float4*)&w1[0], u1b = *(const float4*)&w1[4];
    float4 u2a = *(const float4*)&w2[0], u2b = *(const float4*)&w2[4];
    p1a.x += a * u1a.x; p1a.y += a * u1a.y; p1a.z += a * u1a.z; p1a.w += a * u1a.w;
    p1b.x += a * u1b.x; p1b.y += a * u1b.y; p1b.z += a * u1b.z; p1b.w += a * u1b.w;
    p2a.x += a * u2a.x; p2a.y += a * u2a.y; p2a.z += a * u2a.z; p2a.w += a * u2a.w;
    p2b.x += a * u2b.x; p2b.y += a * u2b.y; p2b.z += a * u2b.z; p2b.w += a * u2b.w;
  }
  *(float4*)&D.P1[(size_t)(node0 + m) * 256 + c0]     = p1a;
  *(float4*)&D.P1[(size_t)(node0 + m) * 256 + c0 + 4] = p1b;
  *(float4*)&D.P2[(size_t)(node0 + m) * 256 + c0]     = p2a;
  *(float4*)&D.P2[(size_t)(node0 + m) * 256 + c0 + 4] = p2b;
}

// ---------------- fused edge-MLP + sparse coalesce + masked gumbel top-5 (r7 verbatim) --
__global__ __launch_bounds__(256) void row_topk(
    const float* __restrict__ P1pp, const float* __restrict__ P2pp,
    const float* __restrict__ b1pp, const float* __restrict__ W2pp,
    const float* __restrict__ b2pp,
    const float* __restrict__ P1aa, const float* __restrict__ P2aa,
    const float* __restrict__ b1aa, const float* __restrict__ W2aa,
    const float* __restrict__ b2aa,
    const int* __restrict__ cnt, const int* __restrict__ entries,
    float* __restrict__ w_pp, float* __restrict__ w_aa,
    uint32_t kpp0, uint32_t kpp1, uint32_t kaa0, uint32_t kaa1)
{
  __shared__ float P1s[256], b1s[256], w2s[256];
  __shared__ int   dS[128];
  __shared__ float pS[128];
  __shared__ int   sel5[KSEL];
  int blk = blockIdx.x, tid = threadIdx.x;
  int lane = tid & 63, wv = tid >> 6;
  int row, Ncols, shift, co; unsigned mask;
  const float* P1; const float* P2; const float* b1; const float* W2; const float* b2;
  float* wout; uint32_t k0, k1;
  if (blk < NPn) {
    row = blk; Ncols = NPn; shift = 18; mask = 0x3FFFFu; co = 12288;
    P1 = P1pp; P2 = P2pp; b1 = b1pp; W2 = W2pp; b2 = b2pp;
    wout = w_pp; k0 = kpp0; k1 = kpp1;
  } else {
    row = blk - NPn; Ncols = NAn; shift = 16; mask = 0xFFFFu; co = 16384;
    P1 = P1aa; P2 = P2aa; b1 = b1aa; W2 = W2aa; b2 = b2aa;
    wout = w_aa; k0 = kaa0; k1 = kaa1;
  }
  const int* ent = entries + (size_t)(co + row) * BSLOT;
  int deg = cnt[co + row];
  P1s[tid] = P1[(size_t)row * 256 + tid];
  b1s[tid] = b1[tid];
  w2s[tid] = W2[tid * 2];
  __syncthreads();
  float bias2 = b2[0];
  int j = lane << 2;
  for (int k = wv * 4; k < deg; k += 16) {
    int n = deg - k; if (n > 4) n = 4;
    unsigned pl0 = (unsigned)ent[k];
    unsigned pl1 = (n > 1) ? (unsigned)ent[k + 1] : pl0;
    unsigned pl2 = (n > 2) ? (unsigned)ent[k + 2] : pl0;
    unsigned pl3 = (n > 3) ? (unsigned)ent[k + 3] : pl0;
    int d0 = (int)(pl0 >> shift), d1 = (int)(pl1 >> shift);
    int d2 = (int)(pl2 >> shift), d3 = (int)(pl3 >> shift);
    float4 q0 = *(const float4*)&P2[(size_t)d0 * 256 + j];
    float4 q1 = *(const float4*)&P2[(size_t)d1 * 256 + j];
    float4 q2 = *(const float4*)&P2[(size_t)d2 * 256 + j];
    float4 q3 = *(const float4*)&P2[(size_t)d3 * 256 + j];
    float pa = P1s[j + 0], pb = P1s[j + 1], pc = P1s[j + 2], pd = P1s[j + 3];
    float ba = b1s[j + 0], bb = b1s[j + 1], bc_ = b1s[j + 2], bd = b1s[j + 3];
    float wa = w2s[j + 0], wb = w2s[j + 1], wc = w2s[j + 2], wd = w2s[j + 3];
    float s0 = fmaxf(pa + q0.x + ba, 0.f) * wa + fmaxf(pb + q0.y + bb, 0.f) * wb +
               fmaxf(pc + q0.z + bc_, 0.f) * wc + fmaxf(pd + q0.w + bd, 0.f) * wd;
    float s1 = fmaxf(pa + q1.x + ba, 0.f) * wa + fmaxf(pb + q1.y + bb, 0.f) * wb +
               fmaxf(pc + q1.z + bc_, 0.f) * wc + fmaxf(pd + q1.w + bd, 0.f) * wd;
    float s2 = fmaxf(pa + q2.x + ba, 0.f) * wa + fmaxf(pb + q2.y + bb, 0.f) * wb +
               fmaxf(pc + q2.z + bc_, 0.f) * wc + fmaxf(pd + q2.w + bd, 0.f) * wd;
    float s3 = fmaxf(pa + q3.x + ba, 0.f) * wa + fmaxf(pb + q3.y + bb, 0.f) * wb +
               fmaxf(pc + q3.z + bc_, 0.f) * wc + fmaxf(pd + q3.w + bd, 0.f) * wd;
    for (int off = 32; off; off >>= 1) {
      s0 += __shfl_down(s0, off);
      s1 += __shfl_down(s1, off);
      s2 += __shfl_down(s2, off);
      s3 += __shfl_down(s3, off);
    }
    if (lane == 0) {
      dS[k] = d0; pS[k] = s0 + bias2;
      if (n > 1) { dS[k + 1] = d1; pS[k + 1] = s1 + bias2; }
      if (n > 2) { dS[k + 2] = d2; pS[k + 2] = s2 + bias2; }
      if (n > 3) { dS[k + 3] = d3; pS[k + 3] = s3 + bias2; }
    }
  }
  __syncthreads();
  if (deg > 0 && wv == 0) {
    int   e0 = (lane < deg) ? dS[lane] : -1;
    float q0v = (lane < deg) ? pS[lane] : 0.f;
    bool  two = (deg > 64);
    int   e1 = -1; float q1v = 0.f;
    if (two && 64 + lane < deg) { e1 = dS[64 + lane]; q1v = pS[64 + lane]; }
    float a0 = 0.f, a1 = 0.f;
    bool lead0 = (e0 >= 0), lead1 = (e1 >= 0);
    for (int j2 = 0; j2 < deg; ++j2) {
      int bj; float bp;
      if (j2 < 64) { bj = __shfl(e0, j2); bp = __shfl(q0v, j2); }
      else         { bj = __shfl(e1, j2 - 64); bp = __shfl(q1v, j2 - 64); }
      if (e0 >= 0 && bj == e0) { a0 += bp; if (j2 < lane) lead0 = false; }
      if (e1 >= 0 && bj == e1) { a1 += bp; if (j2 < 64 + lane) lead1 = false; }
    }
    uint32_t rowbase = (uint32_t)row * (uint32_t)Ncols;
    float y0 = -1e9f, y1 = -1e9f;
    bool c0 = lead0 && (a0 > 0.f);
    if (c0) {
      uint32_t x0 = 0u, x1 = rowbase + (uint32_t)e0;
      tf2x32(k0, k1, x0, x1);
      uint32_t bits = x0 ^ x1;
      float fv = __uint_as_float((bits >> 9) | 0x3f800000u) - 1.0f;
      float u = fmaxf(1e-10f, fv + 1e-10f);
      y0 = a0 + (-logf(-logf(u)));
    }
    bool c1 = lead1 && (a1 > 0.f);
    if (c1) {
      uint32_t x0 = 0u, x1 = rowbase + (uint32_t)e1;
      tf2x32(k0, k1, x0, x1);
      uint32_t bits = x0 ^ x1;
      float fv = __uint_as_float((bits >> 9) | 0x3f800000u) - 1.0f;
      float u = fmaxf(1e-10f, fv + 1e-10f);
      y1 = a1 + (-logf(-logf(u)));
    }
    int cnt2 = __popcll(__ballot(c0)) + __popcll(__ballot(c1));
    int nsel = cnt2 < KSEL ? cnt2 : KSEL;
    for (int it = 0; it < nsel; ++it) {
      float best; int bc;
      if (y1 > y0 || (y1 == y0 && (unsigned)e1 < (unsigned)e0)) { best = y1; bc = e1; }
      else { best = y0; bc = e0; }
      for (int mm = 32; mm; mm >>= 1) {
        float ov = __shfl_xor(best, mm); int oc = __shfl_xor(bc, mm);
        if (ov > best || (ov == best && (unsigned)oc < (unsigned)bc)) { best = ov; bc = oc; }
      }
      if (lane == 0) sel5[it] = bc;
      if (e0 == bc) y0 = -3.0e38f;
      if (e1 == bc) y1 = -3.0e38f;
    }
    if (nsel < KSEL && lane == 0) {
      int c = 0;
      for (int it = nsel; it < KSEL; ++it) {
        for (;;) {
          bool used = false;
          for (int q = 0; q < it; ++q) used |= (sel5[q] == c);
          if (!used) break;
          ++c;
        }
        sel5[it] = c++;
      }
    }
  }
  __syncthreads();
  for (int k = tid; k < deg; k += 256) {
    unsigned pl = (unsigned)ent[k];
    int d = (int)(pl >> shift);
    int e = (int)(pl & mask);
    float v = 0.f;
#pragma unroll
    for (int q = 0; q < KSEL; ++q) v = (sel5[q] == d) ? 1.f : v;
    wout[e] = v;
  }
}

// ---------------- fused GNN2-layer1 (single row) + classifier (r7 verbatim) -------------
__global__ __launch_bounds__(128) void final_kernel(
    const float* __restrict__ hp, const float* __restrict__ ha,
    const int* __restrict__ idxPtr, const float* __restrict__ wpp,
    const int* __restrict__ cnt, const int* __restrict__ entries,
    const float* __restrict__ Wself, const float* __restrict__ Wpp,
    const float* __restrict__ Wap,
    const float* __restrict__ Wc, const float* __restrict__ bc,
    float* __restrict__ out)
{
  __shared__ float selfr[128], mpp[128], mapr[128], t[128];
  int tid = threadIdx.x;
  int idx = idxPtr[0];
  selfr[tid] = hp[(size_t)idx * 128 + tid];
  {
    int deg = cnt[idx];                                   // pp-dst bucket
    const int* ent = entries + (size_t)idx * BSLOT;
    float acc = 0.f;
    for (int k = 0; k < deg; ++k) {
      unsigned pl = (unsigned)ent[k];
      int s = (int)(pl >> 18);
      int e = (int)(pl & 0x3FFFFu);
      acc += wpp[e] * hp[(size_t)s * 128 + tid];
    }
    mpp[tid] = acc / fmaxf((float)deg, 1.0f);
  }
  {
    int deg = cnt[8192 + idx];                            // ap-dst bucket
    const int* ent = entries + (size_t)(8192 + idx) * BSLOT;
    float acc = 0.f;
    for (int k = 0; k < deg; ++k) {
      int s = ent[k];
      acc += ha[(size_t)s * 128 + tid];
    }
    mapr[tid] = acc / fmaxf((float)deg, 1.0f);
  }
  __syncthreads();
  float s = 0.f;
  for (int m = 0; m < 128; ++m) {
    s += selfr[m] * Wself[m * 128 + tid] + mpp[m] * Wpp[m * 128 + tid] +
         mapr[m] * Wap[m * 128 + tid];
  }
  t[tid] = fmaxf(s, 0.f);
  __syncthreads();
  if (tid < 5) {
    float y = bc[tid];
    for (int k = 0; k < 128; ++k) y += t[k] * Wc[k * 5 + tid];
    out[tid] = y;
  }
}

}  // namespace

extern "C" void kernel_launch(void* const* d_in, const int* in_sizes, int n_in,
                              void* d_out, int out_size, void* d_ws, size_t ws_size,
                              hipStream_t stream)
{
  (void)in_sizes; (void)n_in; (void)out_size; (void)ws_size;
  const float* x_p = (const float*)d_in[0];
  const float* x_a = (const float*)d_in[1];
  const int* ei_pp = (const int*)d_in[2];
  const int* ei_aa = (const int*)d_in[3];
  const int* ei_pa = (const int*)d_in[4];
  const int* ei_ap = (const int*)d_in[5];
  const int* idxPtr = (const int*)d_in[8];
  const float* Wself_p0 = (const float*)d_in[9];
  const float* Wself_p1 = (const float*)d_in[10];
  const float* Wself_a0 = (const float*)d_in[11];
  const float* Wself_a1 = (const float*)d_in[12];
  const float* Wpp0 = (const float*)d_in[13]; const float* Wpp1 = (const float*)d_in[14];
  const float* Waa0 = (const float*)d_in[15]; const float* Waa1 = (const float*)d_in[16];
  const float* Wpa0 = (const float*)d_in[17]; /* Wpa1 unused: author L1 dropped */
  const float* Wap0 = (const float*)d_in[19]; const float* Wap1 = (const float*)d_in[20];
  const float* Wep1_pp = (const float*)d_in[21]; const float* bep1_pp = (const float*)d_in[22];
  const float* Wep2_pp = (const float*)d_in[23]; const float* bep2_pp = (const float*)d_in[24];
  const float* Wep1_aa = (const float*)d_in[25]; const float* bep1_aa = (const float*)d_in[26];
  const float* Wep2_aa = (const float*)d_in[27]; const float* bep2_aa = (const float*)d_in[28];
  const float* Wc = (const float*)d_in[29]; const float* bc = (const float*)d_in[30];

  float* out = (float*)d_out;
  float* w_pp_out = out + 5;
  float* w_aa_out = out + 5 + EPPc;

  const int* src_pp = ei_pp;  const int* dst_pp = ei_pp + EPPc;
  const int* src_aa = ei_aa;  const int* dst_aa = ei_aa + EAAc;
  const int* src_pa = ei_pa;  const int* dst_pa = ei_pa + 131072;
  const int* src_ap = ei_ap;  const int* dst_ap = ei_ap + 131072;

  // ---- workspace layout (bump allocator; cnt first: it gets memset) ----
  char* p = (char*)d_ws;
  auto alloc = [&](size_t bytes) -> void* {
    void* r = (void*)p;
    p += (bytes + 255) & ~(size_t)255;
    return r;
  };
  int* cnt     = (int*)alloc(18432 * sizeof(int));
  int* entries = (int*)alloc((size_t)18432 * BSLOT * sizeof(int));  // 9.4 MB buckets
  float* Map  = (float*)alloc((size_t)NPn * Hh * sizeof(float));
  float* Mpa  = (float*)alloc((size_t)NAn * Hh * sizeof(float));
  float* h1p0 = (float*)alloc((size_t)NPn * Hh * sizeof(float));
  float* h1a0 = (float*)alloc((size_t)NAn * Hh * sizeof(float));
  float* h2p0 = (float*)alloc((size_t)NPn * Hh * sizeof(float));
  float* h2a0 = (float*)alloc((size_t)NAn * Hh * sizeof(float));
  float* P1pp = (float*)alloc((size_t)NPn * 256 * sizeof(float));
  float* P2pp = (float*)alloc((size_t)NPn * 256 * sizeof(float));
  float* P1aa = (float*)alloc((size_t)NAn * 256 * sizeof(float));
  float* P2aa = (float*)alloc((size_t)NAn * 256 * sizeof(float));

  // bucket cnt offsets
  const int CO_PPD = 0, CO_AAD = 4096, CO_PAD = 6144, CO_APD = 8192;

  hipMemsetAsync(cnt, 0, 18432 * sizeof(int), stream);
  scatter_kernel<<<2560, 256, 0, stream>>>(src_pp, dst_pp, src_aa, dst_aa,
                                           src_pa, dst_pa, src_ap, dst_ap,
                                           cnt, entries);

  // ---- K1: GNN1-L0 fused (agg+gemm) + agg-only Map/Mpa ----
  {
    FArgs fa{};
    fa.d[0] = {x_p, nullptr, CO_PPD, 18, nullptr,
               x_p, Wself_p0, Wpp0, nullptr, nullptr, h1p0, 1,
               nullptr, nullptr, nullptr};
    fa.d[1] = {x_a, nullptr, CO_AAD, 16, nullptr,
               x_a, Wself_a0, Waa0, nullptr, nullptr, h1a0, 1,
               nullptr, nullptr, nullptr};
    fa.d[2] = {x_a, nullptr, CO_APD, 0, Map,
               nullptr, nullptr, nullptr, nullptr, nullptr, nullptr, 0,
               nullptr, nullptr, nullptr};
    fa.d[3] = {x_p, nullptr, CO_PAD, 0, Mpa,
               nullptr, nullptr, nullptr, nullptr, nullptr, nullptr, 0,
               nullptr, nullptr, nullptr};
    fa.bstart[0] = 0; fa.bstart[1] = 512; fa.bstart[2] = 768;
    fa.bstart[3] = 1280; fa.bstart[4] = 1536; fa.nd = 4;
    fused_layer<<<1536, 256, 0, stream>>>(fa, cnt, entries);
  }

  // ---- K2: GNN1-L1 fused (agg+gemm) + P projections; h1p1 never materialized ----
  {
    FArgs fa{};
    fa.d[0] = {h1p0, nullptr, CO_PPD, 18, nullptr,
               h1p0, Wself_p1, Wpp1, nullptr, nullptr, nullptr, 1,
               Wep1_pp, P1pp, P2pp};
    fa.d[1] = {h1a0, nullptr, CO_AAD, 16, nullptr,
               h1a0, Wself_a1, Waa1, nullptr, nullptr, nullptr, 1,
               Wep1_aa, P1aa, P2aa};
    fa.bstart[0] = 0; fa.bstart[1] = 512; fa.bstart[2] = 768; fa.nd = 2;
    fused_layer<<<768, 256, 0, stream>>>(fa, cnt, entries);
  }

  // ---- JAX keys: key(42) -> split -> (kpp, kaa) (partitionable fold-in) ----
  uint32_t kpp0, kpp1, kaa0, kaa1;
  { uint32_t a0 = 0, a1 = 0; tf2x32(0u, 42u, a0, a1); kpp0 = a0; kpp1 = a1; }
  { uint32_t a0 = 0, a1 = 1; tf2x32(0u, 42u, a0, a1); kaa0 = a0; kaa1 = a1; }

  // ---- fused edge-pred + sparse coalesce + gumbel top-5 + w write ----
  row_topk<<<NPn + NAn, 256, 0, stream>>>(P1pp, P2pp, bep1_pp, Wep2_pp, bep2_pp,
                                          P1aa, P2aa, bep1_aa, Wep2_aa, bep2_aa,
                                          cnt, entries, w_pp_out, w_aa_out,
                                          kpp0, kpp1, kaa0, kaa1);

  // ---- K3: GNN2-L0 fused (weighted agg + 3-part gemm; Map/Mpa from K1) ----
  {
    FArgs fa{};
    fa.d[0] = {x_p, w_pp_out, CO_PPD, 18, nullptr,
               x_p, Wself_p0, Wpp0, Map, Wap0, h2p0, 1,
               nullptr, nullptr, nullptr};
    fa.d[1] = {x_a, w_aa_out, CO_AAD, 16, nullptr,
               x_a, Wself_a0, Waa0, Mpa, Wpa0, h2a0, 1,
               nullptr, nullptr, nullptr};
    fa.bstart[0] = 0; fa.bstart[1] = 512; fa.bstart[2] = 768; fa.nd = 2;
    fused_layer<<<768, 256, 0, stream>>>(fa, cnt, entries);
  }

  // ---- GNN2 layer 1 only needed at one paper row -> fused with classifier ----
  final_kernel<<<1, 128, 0, stream>>>(h2p0, h2a0, idxPtr, w_pp_out,
                                      cnt, entries,
                                      Wself_p1, Wpp1, Wap1, Wc, bc, out);
}